// Round 1
// baseline (462.649 us; speedup 1.0000x reference)
//
#include <hip/hip_runtime.h>
#include <math.h>

#define F 128
#define OUT 128

// ---------------------------------------------------------------------------
// Kernel A: proj_dst[i][j] = sum_k feat[i][k]*w1[k][j] + b1[j]
//           proj_src[i][j] = sum_k feat[i][k]*w1[F+k][j]
// 8 node-rows per block, 256 threads: half = t>>7 (0=dst,1=src), j = t&127.
// ---------------------------------------------------------------------------
__global__ __launch_bounds__(256) void proj_kernel(
    const float* __restrict__ feat, const float* __restrict__ w1,
    const float* __restrict__ b1, float* __restrict__ proj_dst,
    float* __restrict__ proj_src, int n)
{
    __shared__ float fs[8][F];
    const int block_row = blockIdx.x * 8;
    const int t = threadIdx.x;

    for (int i = t; i < 8 * F; i += 256) {
        int m = i >> 7, k = i & (F - 1);
        int row = block_row + m;
        fs[m][k] = (row < n) ? feat[(size_t)row * F + k] : 0.f;
    }
    __syncthreads();

    const int half = t >> 7;
    const int j = t & (F - 1);
    float acc[8];
#pragma unroll
    for (int m = 0; m < 8; ++m) acc[m] = 0.f;

    const float* w = w1 + (size_t)half * F * F + j;
    for (int k = 0; k < F; ++k) {
        float wv = w[(size_t)k * F];
#pragma unroll
        for (int m = 0; m < 8; ++m) acc[m] += fs[m][k] * wv;
    }

    const float bb = (half == 0) ? b1[j] : 0.f;
    float* outp = (half == 0) ? proj_dst : proj_src;
#pragma unroll
    for (int m = 0; m < 8; ++m) {
        int row = block_row + m;
        if (row < n) outp[(size_t)row * F + j] = acc[m] + bb;
    }
}

// ---------------------------------------------------------------------------
// Kernel B: row_ptr[v] = first edge index with dst >= v  (dst is sorted)
// ---------------------------------------------------------------------------
__global__ void rowptr_kernel(const int* __restrict__ dst,
                              int* __restrict__ row_ptr, int e, int n)
{
    int i = blockIdx.x * blockDim.x + threadIdx.x;
    if (i >= e) return;
    int d = dst[i];
    int prev = (i == 0) ? -1 : dst[i - 1];
    for (int v = prev + 1; v <= d; ++v) row_ptr[v] = i;
    if (i == e - 1) {
        for (int v = d + 1; v <= n; ++v) row_ptr[v] = e;
    }
}

// ---------------------------------------------------------------------------
// Kernel C: one wave per edge.
// scores[e] = b2 + sum_f tanh(proj_dst[dst][f] + proj_src[src][f]) * w2[f]
// (b1 already folded into proj_dst)
// ---------------------------------------------------------------------------
__global__ __launch_bounds__(256) void score_kernel(
    const float* __restrict__ proj_dst, const float* __restrict__ proj_src,
    const int* __restrict__ src, const int* __restrict__ dst,
    const float* __restrict__ w2, const float* __restrict__ b2,
    float* __restrict__ scores, int e)
{
    const int wave = (int)((blockIdx.x * (size_t)blockDim.x + threadIdx.x) >> 6);
    const int lane = threadIdx.x & 63;
    if (wave >= e) return;

    const int s = src[wave];
    const int d = dst[wave];
    const float2 a = ((const float2*)(proj_dst + (size_t)d * F))[lane];
    const float2 b = ((const float2*)(proj_src + (size_t)s * F))[lane];
    const float2 w = ((const float2*)w2)[lane];

    float v = tanhf(a.x + b.x) * w.x + tanhf(a.y + b.y) * w.y;
#pragma unroll
    for (int off = 32; off; off >>= 1) v += __shfl_down(v, off, 64);
    if (lane == 0) scores[wave] = v + b2[0];
}

// ---------------------------------------------------------------------------
// Kernel D (fused): per-node softmax over incoming edges + weighted
// aggregation of feat[src] + output GEMM with wf.
// One 128-thread block (2 waves) per node.
// ---------------------------------------------------------------------------
__global__ __launch_bounds__(128) void agg_kernel(
    const float* __restrict__ feat, const int* __restrict__ src,
    const int* __restrict__ row_ptr, const float* __restrict__ scores,
    const float* __restrict__ wf, const float* __restrict__ bf,
    float* __restrict__ out)
{
    const int v = blockIdx.x;
    const int t = threadIdx.x;

    __shared__ float fs[F];
    __shared__ float ns[F];
    __shared__ float red[4];

    const int begin = row_ptr[v];
    const int end = row_ptr[v + 1];
    const int deg = end - begin;

    fs[t] = feat[(size_t)v * F + t];

    float neigh = 0.f;
    if (deg > 0) {
        // --- block max of scores ---
        float mx = -INFINITY;
        for (int e = begin + t; e < end; e += 128) mx = fmaxf(mx, scores[e]);
#pragma unroll
        for (int off = 32; off; off >>= 1) mx = fmaxf(mx, __shfl_down(mx, off, 64));
        if ((t & 63) == 0) red[t >> 6] = mx;
        __syncthreads();
        mx = fmaxf(red[0], red[1]);

        // --- block sum of exp ---
        float sum = 0.f;
        for (int e = begin + t; e < end; e += 128) sum += __expf(scores[e] - mx);
#pragma unroll
        for (int off = 32; off; off >>= 1) sum += __shfl_down(sum, off, 64);
        if ((t & 63) == 0) red[2 + (t >> 6)] = sum;
        __syncthreads();
        const float inv = 1.f / (red[2] + red[3]);

        // --- weighted aggregation: thread t owns feature t ---
        for (int e = begin; e < end; ++e) {
            float wgt = __expf(scores[e] - mx);
            neigh += wgt * feat[(size_t)src[e] * F + t];
        }
        neigh *= inv;
    }
    ns[t] = neigh;
    __syncthreads();

    // --- output GEMM: thread t owns output column t ---
    float o = bf[t];
    const float* w0 = wf + t;
    for (int k = 0; k < F; ++k) {
        o += fs[k] * w0[(size_t)k * OUT] + ns[k] * w0[(size_t)(F + k) * OUT];
    }
    out[(size_t)v * OUT + t] = o;
}

// ---------------------------------------------------------------------------
extern "C" void kernel_launch(void* const* d_in, const int* in_sizes, int n_in,
                              void* d_out, int out_size, void* d_ws, size_t ws_size,
                              hipStream_t stream)
{
    const float* feat = (const float*)d_in[0];
    const int*   src  = (const int*)d_in[1];
    const int*   dst  = (const int*)d_in[2];
    const float* w1   = (const float*)d_in[3];
    const float* b1   = (const float*)d_in[4];
    const float* w2   = (const float*)d_in[5];
    const float* b2   = (const float*)d_in[6];
    const float* wf   = (const float*)d_in[7];
    const float* bf   = (const float*)d_in[8];
    float* out = (float*)d_out;

    const int n = in_sizes[0] / F;   // 40000
    const int e = in_sizes[1];       // 640000

    float* proj_dst = (float*)d_ws;
    float* proj_src = proj_dst + (size_t)n * F;
    float* scores   = proj_src + (size_t)n * F;
    int*   row_ptr  = (int*)(scores + e);

    proj_kernel<<<(n + 7) / 8, 256, 0, stream>>>(feat, w1, b1, proj_dst, proj_src, n);
    rowptr_kernel<<<(e + 255) / 256, 256, 0, stream>>>(dst, row_ptr, e, n);
    score_kernel<<<(e + 3) / 4, 256, 0, stream>>>(proj_dst, proj_src, src, dst,
                                                  w2, b2, scores, e);
    agg_kernel<<<n, 128, 0, stream>>>(feat, src, row_ptr, scores, wf, bf, out);
}

// Round 2
// 409.908 us; speedup vs baseline: 1.1287x; 1.1287x over previous
//
#include <hip/hip_runtime.h>
#include <math.h>

#define F 128
#define OUT 128

__device__ __forceinline__ float fast_tanh(float x) {
    // tanh(x) = 1 - 2/(exp(2x)+1); exact limits at +/-inf, no branches.
    float e = __expf(2.f * x);
    return 1.f - __fdividef(2.f, e + 1.f);
}

// ---------------------------------------------------------------------------
// Kernel A: proj_dst[i][j] = sum_k feat[i][k]*w1[k][j] + b1[j]
//           proj_src[i][j] = sum_k feat[i][k]*w1[F+k][j]
// 8 node-rows per block, 256 threads: half = t>>7 (0=dst,1=src), j = t&127.
// ---------------------------------------------------------------------------
__global__ __launch_bounds__(256) void proj_kernel(
    const float* __restrict__ feat, const float* __restrict__ w1,
    const float* __restrict__ b1, float* __restrict__ proj_dst,
    float* __restrict__ proj_src, int n)
{
    __shared__ float fs[8][F];
    const int block_row = blockIdx.x * 8;
    const int t = threadIdx.x;

    for (int i = t; i < 8 * F; i += 256) {
        int m = i >> 7, k = i & (F - 1);
        int row = block_row + m;
        fs[m][k] = (row < n) ? feat[(size_t)row * F + k] : 0.f;
    }
    __syncthreads();

    const int half = t >> 7;
    const int j = t & (F - 1);
    float acc[8];
#pragma unroll
    for (int m = 0; m < 8; ++m) acc[m] = 0.f;

    const float* w = w1 + (size_t)half * F * F + j;
    for (int k = 0; k < F; ++k) {
        float wv = w[(size_t)k * F];
#pragma unroll
        for (int m = 0; m < 8; ++m) acc[m] += fs[m][k] * wv;
    }

    const float bb = (half == 0) ? b1[j] : 0.f;
    float* outp = (half == 0) ? proj_dst : proj_src;
#pragma unroll
    for (int m = 0; m < 8; ++m) {
        int row = block_row + m;
        if (row < n) outp[(size_t)row * F + j] = acc[m] + bb;
    }
}

// ---------------------------------------------------------------------------
// Kernel B: row_ptr[v] = first edge index with dst >= v  (dst is sorted)
// ---------------------------------------------------------------------------
__global__ void rowptr_kernel(const int* __restrict__ dst,
                              int* __restrict__ row_ptr, int e, int n)
{
    int i = blockIdx.x * blockDim.x + threadIdx.x;
    if (i >= e) return;
    int d = dst[i];
    int prev = (i == 0) ? -1 : dst[i - 1];
    for (int v = prev + 1; v <= d; ++v) row_ptr[v] = i;
    if (i == e - 1) {
        for (int v = d + 1; v <= n; ++v) row_ptr[v] = e;
    }
}

// ---------------------------------------------------------------------------
// Kernel C: one wave per edge.
// scores[e] = b2 + sum_f tanh(proj_dst[dst][f] + proj_src[src][f]) * w2[f]
// (b1 already folded into proj_dst)
// ---------------------------------------------------------------------------
__global__ __launch_bounds__(256) void score_kernel(
    const float* __restrict__ proj_dst, const float* __restrict__ proj_src,
    const int* __restrict__ src, const int* __restrict__ dst,
    const float* __restrict__ w2, const float* __restrict__ b2,
    float* __restrict__ scores, int e)
{
    const int wave = (int)((blockIdx.x * (size_t)blockDim.x + threadIdx.x) >> 6);
    const int lane = threadIdx.x & 63;
    if (wave >= e) return;

    const int s = src[wave];
    const int d = dst[wave];
    const float2 a = ((const float2*)(proj_dst + (size_t)d * F))[lane];
    const float2 b = ((const float2*)(proj_src + (size_t)s * F))[lane];
    const float2 w = ((const float2*)w2)[lane];

    float v = fast_tanh(a.x + b.x) * w.x + fast_tanh(a.y + b.y) * w.y;
#pragma unroll
    for (int off = 32; off; off >>= 1) v += __shfl_down(v, off, 64);
    if (lane == 0) scores[wave] = v + b2[0];
}

// ---------------------------------------------------------------------------
// Kernel D: per-node softmax over incoming edges + weighted aggregation of
// feat[src]. Writes neigh[N][F] to workspace. One 128-thread block per node.
// ---------------------------------------------------------------------------
__global__ __launch_bounds__(128) void agg_kernel(
    const float* __restrict__ feat, const int* __restrict__ src,
    const int* __restrict__ row_ptr, const float* __restrict__ scores,
    float* __restrict__ neigh_out)
{
    const int v = blockIdx.x;
    const int t = threadIdx.x;

    __shared__ float red[4];

    const int begin = row_ptr[v];
    const int end = row_ptr[v + 1];
    const int deg = end - begin;

    float neigh = 0.f;
    if (deg > 0) {
        // --- block max of scores ---
        float mx = -INFINITY;
        for (int e = begin + t; e < end; e += 128) mx = fmaxf(mx, scores[e]);
#pragma unroll
        for (int off = 32; off; off >>= 1) mx = fmaxf(mx, __shfl_down(mx, off, 64));
        if ((t & 63) == 0) red[t >> 6] = mx;
        __syncthreads();
        mx = fmaxf(red[0], red[1]);

        // --- block sum of exp ---
        float sum = 0.f;
        for (int e = begin + t; e < end; e += 128) sum += __expf(scores[e] - mx);
#pragma unroll
        for (int off = 32; off; off >>= 1) sum += __shfl_down(sum, off, 64);
        if ((t & 63) == 0) red[2 + (t >> 6)] = sum;
        __syncthreads();
        const float inv = 1.f / (red[2] + red[3]);

        // --- weighted aggregation: thread t owns feature t ---
        for (int e = begin; e < end; ++e) {
            float wgt = __expf(scores[e] - mx);
            neigh += wgt * feat[(size_t)src[e] * F + t];
        }
        neigh *= inv;
    }
    neigh_out[(size_t)v * F + t] = neigh;
}

// ---------------------------------------------------------------------------
// Kernel E: out = feat @ wf[:F] + neigh @ wf[F:] + bf
// 8 node-rows per block, 256 threads = 2 k-halves x 128 cols.
// ---------------------------------------------------------------------------
__global__ __launch_bounds__(256) void out_kernel(
    const float* __restrict__ feat, const float* __restrict__ neigh,
    const float* __restrict__ wf, const float* __restrict__ bf,
    float* __restrict__ out, int n)
{
    __shared__ float xs[2][8][F];   // [half][row][k]: half0=feat, half1=neigh
    __shared__ float part[8][F];
    const int block_row = blockIdx.x * 8;
    const int t = threadIdx.x;
    const int h = t >> 7;
    const int j = t & (F - 1);

    for (int i = t; i < 8 * F; i += 256) {
        int m = i >> 7, k = i & (F - 1);
        int row = block_row + m;
        xs[0][m][k] = (row < n) ? feat[(size_t)row * F + k] : 0.f;
        xs[1][m][k] = (row < n) ? neigh[(size_t)row * F + k] : 0.f;
    }
    __syncthreads();

    float acc[8];
#pragma unroll
    for (int m = 0; m < 8; ++m) acc[m] = 0.f;

    const float* w = wf + (size_t)h * F * OUT + j;
    for (int k = 0; k < F; ++k) {
        float wv = w[(size_t)k * OUT];
#pragma unroll
        for (int m = 0; m < 8; ++m) acc[m] += xs[h][m][k] * wv;
    }

    if (h == 1) {
#pragma unroll
        for (int m = 0; m < 8; ++m) part[m][j] = acc[m];
    }
    __syncthreads();
    if (h == 0) {
        const float bb = bf[j];
#pragma unroll
        for (int m = 0; m < 8; ++m) {
            int row = block_row + m;
            if (row < n) out[(size_t)row * OUT + j] = acc[m] + part[m][j] + bb;
        }
    }
}

// ---------------------------------------------------------------------------
extern "C" void kernel_launch(void* const* d_in, const int* in_sizes, int n_in,
                              void* d_out, int out_size, void* d_ws, size_t ws_size,
                              hipStream_t stream)
{
    const float* feat = (const float*)d_in[0];
    const int*   src  = (const int*)d_in[1];
    const int*   dst  = (const int*)d_in[2];
    const float* w1   = (const float*)d_in[3];
    const float* b1   = (const float*)d_in[4];
    const float* w2   = (const float*)d_in[5];
    const float* b2   = (const float*)d_in[6];
    const float* wf   = (const float*)d_in[7];
    const float* bf   = (const float*)d_in[8];
    float* out = (float*)d_out;

    const int n = in_sizes[0] / F;   // 40000
    const int e = in_sizes[1];       // 640000

    float* proj_dst = (float*)d_ws;
    float* proj_src = proj_dst + (size_t)n * F;
    float* scores   = proj_src + (size_t)n * F;
    float* neigh    = scores + e;
    int*   row_ptr  = (int*)(neigh + (size_t)n * F);

    proj_kernel<<<(n + 7) / 8, 256, 0, stream>>>(feat, w1, b1, proj_dst, proj_src, n);
    rowptr_kernel<<<(e + 255) / 256, 256, 0, stream>>>(dst, row_ptr, e, n);
    score_kernel<<<(e + 3) / 4, 256, 0, stream>>>(proj_dst, proj_src, src, dst,
                                                  w2, b2, scores, e);
    agg_kernel<<<n, 128, 0, stream>>>(feat, src, row_ptr, scores, neigh);
    out_kernel<<<(n + 7) / 8, 256, 0, stream>>>(feat, neigh, wf, bf, out, n);
}

// Round 3
// 342.129 us; speedup vs baseline: 1.3523x; 1.1981x over previous
//
#include <hip/hip_runtime.h>
#include <math.h>

#define F 128
#define OUT 128

__device__ __forceinline__ float fast_tanh(float x) {
    // tanh(x) = 1 - 2/(exp(2x)+1); exact limits at +/-inf, no branches.
    float e = __expf(2.f * x);
    return 1.f - __fdividef(2.f, e + 1.f);
}

// ---------------------------------------------------------------------------
// Kernel A: proj_dst[i][j] = sum_k feat[i][k]*w1[k][j] + b1[j]
//           proj_src[i][j] = sum_k feat[i][k]*w1[F+k][j]
// 8 node-rows per block, 256 threads: half = t>>7 (0=dst,1=src), j = t&127.
// ---------------------------------------------------------------------------
__global__ __launch_bounds__(256) void proj_kernel(
    const float* __restrict__ feat, const float* __restrict__ w1,
    const float* __restrict__ b1, float* __restrict__ proj_dst,
    float* __restrict__ proj_src, int n)
{
    __shared__ float fs[8][F];
    const int block_row = blockIdx.x * 8;
    const int t = threadIdx.x;

    for (int i = t; i < 8 * F; i += 256) {
        int m = i >> 7, k = i & (F - 1);
        int row = block_row + m;
        fs[m][k] = (row < n) ? feat[(size_t)row * F + k] : 0.f;
    }
    __syncthreads();

    const int half = t >> 7;
    const int j = t & (F - 1);
    float acc[8];
#pragma unroll
    for (int m = 0; m < 8; ++m) acc[m] = 0.f;

    const float* w = w1 + (size_t)half * F * F + j;
    for (int k = 0; k < F; ++k) {
        float wv = w[(size_t)k * F];
#pragma unroll
        for (int m = 0; m < 8; ++m) acc[m] += fs[m][k] * wv;
    }

    const float bb = (half == 0) ? b1[j] : 0.f;
    float* outp = (half == 0) ? proj_dst : proj_src;
#pragma unroll
    for (int m = 0; m < 8; ++m) {
        int row = block_row + m;
        if (row < n) outp[(size_t)row * F + j] = acc[m] + bb;
    }
}

// ---------------------------------------------------------------------------
// Kernel B: row_ptr[v] = first edge index with dst >= v  (dst is sorted)
// ---------------------------------------------------------------------------
__global__ void rowptr_kernel(const int* __restrict__ dst,
                              int* __restrict__ row_ptr, int e, int n)
{
    int i = blockIdx.x * blockDim.x + threadIdx.x;
    if (i >= e) return;
    int d = dst[i];
    int prev = (i == 0) ? -1 : dst[i - 1];
    for (int v = prev + 1; v <= d; ++v) row_ptr[v] = i;
    if (i == e - 1) {
        for (int v = d + 1; v <= n; ++v) row_ptr[v] = e;
    }
}

// ---------------------------------------------------------------------------
// Kernel C v2: half-wave (32 lanes x float4) per edge, grid-stride.
// scores[e] = b2 + sum_f tanh(proj_dst[dst][f] + proj_src[src][f]) * w2[f]
// w2/b2 hoisted into registers; consecutive edges share dst rows (L1 reuse).
// ---------------------------------------------------------------------------
__global__ __launch_bounds__(256) void score_kernel(
    const float* __restrict__ proj_dst, const float* __restrict__ proj_src,
    const int* __restrict__ src, const int* __restrict__ dst,
    const float* __restrict__ w2, const float* __restrict__ b2,
    float* __restrict__ scores, int e)
{
    const int t = threadIdx.x;
    const int lane = t & 63;
    const int half = lane >> 5;       // which edge of the pair
    const int fl = lane & 31;         // feature-chunk index (4 floats each)

    const float4 w = ((const float4*)w2)[fl];
    const float bb = b2[0];

    const int wid = (blockIdx.x * 256 + t) >> 6;
    const int nwaves = (gridDim.x * 256) >> 6;

    for (int base = wid * 2; base < e; base += nwaves * 2) {
        const int ei = base + half;
        int s = 0, d = 0;
        if (ei < e) { s = src[ei]; d = dst[ei]; }

        const float4 a = ((const float4*)(proj_dst + (size_t)d * F))[fl];
        const float4 b = ((const float4*)(proj_src + (size_t)s * F))[fl];

        float v = fast_tanh(a.x + b.x) * w.x + fast_tanh(a.y + b.y) * w.y
                + fast_tanh(a.z + b.z) * w.z + fast_tanh(a.w + b.w) * w.w;

        // reduce across the 32 lanes of this half (xor keeps within half)
#pragma unroll
        for (int off = 16; off; off >>= 1) v += __shfl_xor(v, off, 64);

        if (fl == 0 && ei < e) scores[ei] = v + bb;
    }
}

// ---------------------------------------------------------------------------
// Kernel D v2: one wave per node; float2 per lane (64*8B = 512B row).
// Fast path deg<=64: scores in registers, softmax via xor-reduce, inner loop
// broadcasts precomputed exp via shfl. Generic fallback for deg>64.
// ---------------------------------------------------------------------------
__global__ __launch_bounds__(256) void agg_kernel(
    const float* __restrict__ feat, const int* __restrict__ src,
    const int* __restrict__ row_ptr, const float* __restrict__ scores,
    float* __restrict__ neigh_out, int n)
{
    const int v = (int)((blockIdx.x * 256u + threadIdx.x) >> 6);
    const int lane = threadIdx.x & 63;
    if (v >= n) return;

    const int begin = row_ptr[v];
    const int end = row_ptr[v + 1];
    const int deg = end - begin;

    float2 acc = {0.f, 0.f};
    if (deg > 0) {
        if (deg <= 64) {
            float sc = (lane < deg) ? scores[begin + lane] : -INFINITY;
            float m = sc;
#pragma unroll
            for (int off = 32; off; off >>= 1) m = fmaxf(m, __shfl_xor(m, off, 64));
            float ex = (lane < deg) ? __expf(sc - m) : 0.f;
            float s = ex;
#pragma unroll
            for (int off = 32; off; off >>= 1) s += __shfl_xor(s, off, 64);
            const float inv = 1.f / s;

            for (int j = 0; j < deg; ++j) {
                const float wgt = __shfl(ex, j, 64);
                const int sr = src[begin + j];
                const float2 f2 = ((const float2*)(feat + (size_t)sr * F))[lane];
                acc.x += wgt * f2.x;
                acc.y += wgt * f2.y;
            }
            acc.x *= inv;
            acc.y *= inv;
        } else {
            float m = -INFINITY;
            for (int e2 = begin + lane; e2 < end; e2 += 64) m = fmaxf(m, scores[e2]);
#pragma unroll
            for (int off = 32; off; off >>= 1) m = fmaxf(m, __shfl_xor(m, off, 64));
            float s = 0.f;
            for (int e2 = begin + lane; e2 < end; e2 += 64) s += __expf(scores[e2] - m);
#pragma unroll
            for (int off = 32; off; off >>= 1) s += __shfl_xor(s, off, 64);
            const float inv = 1.f / s;

            for (int j = begin; j < end; ++j) {
                const float wgt = __expf(scores[j] - m);
                const int sr = src[j];
                const float2 f2 = ((const float2*)(feat + (size_t)sr * F))[lane];
                acc.x += wgt * f2.x;
                acc.y += wgt * f2.y;
            }
            acc.x *= inv;
            acc.y *= inv;
        }
    }
    ((float2*)(neigh_out + (size_t)v * F))[lane] = acc;
}

// ---------------------------------------------------------------------------
// Kernel E: out = feat @ wf[:F] + neigh @ wf[F:] + bf
// 8 node-rows per block, 256 threads = 2 k-halves x 128 cols.
// ---------------------------------------------------------------------------
__global__ __launch_bounds__(256) void out_kernel(
    const float* __restrict__ feat, const float* __restrict__ neigh,
    const float* __restrict__ wf, const float* __restrict__ bf,
    float* __restrict__ out, int n)
{
    __shared__ float xs[2][8][F];   // [half][row][k]: half0=feat, half1=neigh
    __shared__ float part[8][F];
    const int block_row = blockIdx.x * 8;
    const int t = threadIdx.x;
    const int h = t >> 7;
    const int j = t & (F - 1);

    for (int i = t; i < 8 * F; i += 256) {
        int m = i >> 7, k = i & (F - 1);
        int row = block_row + m;
        xs[0][m][k] = (row < n) ? feat[(size_t)row * F + k] : 0.f;
        xs[1][m][k] = (row < n) ? neigh[(size_t)row * F + k] : 0.f;
    }
    __syncthreads();

    float acc[8];
#pragma unroll
    for (int m = 0; m < 8; ++m) acc[m] = 0.f;

    const float* w = wf + (size_t)h * F * OUT + j;
    for (int k = 0; k < F; ++k) {
        float wv = w[(size_t)k * OUT];
#pragma unroll
        for (int m = 0; m < 8; ++m) acc[m] += xs[h][m][k] * wv;
    }

    if (h == 1) {
#pragma unroll
        for (int m = 0; m < 8; ++m) part[m][j] = acc[m];
    }
    __syncthreads();
    if (h == 0) {
        const float bb = bf[j];
#pragma unroll
        for (int m = 0; m < 8; ++m) {
            int row = block_row + m;
            if (row < n) out[(size_t)row * OUT + j] = acc[m] + part[m][j] + bb;
        }
    }
}

// ---------------------------------------------------------------------------
extern "C" void kernel_launch(void* const* d_in, const int* in_sizes, int n_in,
                              void* d_out, int out_size, void* d_ws, size_t ws_size,
                              hipStream_t stream)
{
    const float* feat = (const float*)d_in[0];
    const int*   src  = (const int*)d_in[1];
    const int*   dst  = (const int*)d_in[2];
    const float* w1   = (const float*)d_in[3];
    const float* b1   = (const float*)d_in[4];
    const float* w2   = (const float*)d_in[5];
    const float* b2   = (const float*)d_in[6];
    const float* wf   = (const float*)d_in[7];
    const float* bf   = (const float*)d_in[8];
    float* out = (float*)d_out;

    const int n = in_sizes[0] / F;   // 40000
    const int e = in_sizes[1];       // 640000

    float* proj_dst = (float*)d_ws;
    float* proj_src = proj_dst + (size_t)n * F;
    float* scores   = proj_src + (size_t)n * F;
    float* neigh    = scores + e;
    int*   row_ptr  = (int*)(neigh + (size_t)n * F);

    proj_kernel<<<(n + 7) / 8, 256, 0, stream>>>(feat, w1, b1, proj_dst, proj_src, n);
    rowptr_kernel<<<(e + 255) / 256, 256, 0, stream>>>(dst, row_ptr, e, n);
    score_kernel<<<4096, 256, 0, stream>>>(proj_dst, proj_src, src, dst,
                                           w2, b2, scores, e);
    agg_kernel<<<(n + 3) / 4, 256, 0, stream>>>(feat, src, row_ptr, scores, neigh, n);
    out_kernel<<<(n + 7) / 8, 256, 0, stream>>>(feat, neigh, wf, bf, out, n);
}

// Round 4
// 269.504 us; speedup vs baseline: 1.7167x; 1.2695x over previous
//
#include <hip/hip_runtime.h>
#include <math.h>

#define F 128
#define OUT 128
#define BM 64
#define BN 128
#define BK 32

// ---------------------------------------------------------------------------
// Kernel A v3: register-tiled GEMM, 256 threads, BM=64 x BN=128, TM=4 x TN=4+4.
// grid (n/BM, 2): blockIdx.y==0 -> e_dst = exp(2*(feat@w1[:F] + b1))
//                 blockIdx.y==1 -> e_src = exp(2*(feat@w1[F:]))
// (exp-form lets score_kernel use tanh(a+b) = 1 - 2/(Ea*Eb+1))
// ---------------------------------------------------------------------------
__global__ __launch_bounds__(256) void proj_kernel(
    const float* __restrict__ feat, const float* __restrict__ w1,
    const float* __restrict__ b1, float* __restrict__ e_dst,
    float* __restrict__ e_src, int n)
{
    __shared__ float As[BK][BM];   // transposed feat tile
    __shared__ float Bs[BK][BN];

    const int t  = threadIdx.x;
    const int i0 = blockIdx.x * BM;
    const int h  = blockIdx.y;
    const float* B = w1 + (size_t)h * F * F;   // 128x128 row-major half

    const int g  = t >> 4;          // col group 0..15
    const int mr = (t & 15) * 4;    // row0 of thread tile

    float acc[4][8];
#pragma unroll
    for (int i = 0; i < 4; ++i)
#pragma unroll
        for (int j = 0; j < 8; ++j) acc[i][j] = 0.f;

    for (int k0 = 0; k0 < F; k0 += BK) {
        // load A tile (64 rows x 32 k), transposed into As[k][m]
        {
            int row = t >> 3, c4 = (t & 7) * 4;
            float4 a = ((i0 + row) < n)
                ? *(const float4*)(feat + (size_t)(i0 + row) * F + k0 + c4)
                : make_float4(0.f, 0.f, 0.f, 0.f);
            As[c4 + 0][row] = a.x; As[c4 + 1][row] = a.y;
            As[c4 + 2][row] = a.z; As[c4 + 3][row] = a.w;
            row += 32;
            float4 b = ((i0 + row) < n)
                ? *(const float4*)(feat + (size_t)(i0 + row) * F + k0 + c4)
                : make_float4(0.f, 0.f, 0.f, 0.f);
            As[c4 + 0][row] = b.x; As[c4 + 1][row] = b.y;
            As[c4 + 2][row] = b.z; As[c4 + 3][row] = b.w;
        }
        // load B tile (32 k x 128 n)
#pragma unroll
        for (int q = 0; q < 4; ++q) {
            int idx = t + 256 * q;
            int row = idx >> 5, c4 = (idx & 31) * 4;
            *(float4*)&Bs[row][c4] =
                *(const float4*)(B + (size_t)(k0 + row) * F + c4);
        }
        __syncthreads();

#pragma unroll
        for (int k = 0; k < BK; ++k) {
            float4 a  = *(const float4*)&As[k][mr];
            float4 b0 = *(const float4*)&Bs[k][g * 4];
            float4 b1v = *(const float4*)&Bs[k][64 + g * 4];
            float av[4] = {a.x, a.y, a.z, a.w};
            float bv[8] = {b0.x, b0.y, b0.z, b0.w, b1v.x, b1v.y, b1v.z, b1v.w};
#pragma unroll
            for (int i = 0; i < 4; ++i)
#pragma unroll
                for (int j = 0; j < 8; ++j)
                    acc[i][j] = fmaf(av[i], bv[j], acc[i][j]);
        }
        __syncthreads();
    }

    float* outp = (h == 0) ? e_dst : e_src;
    float4 bb0 = make_float4(0.f, 0.f, 0.f, 0.f), bb1 = bb0;
    if (h == 0) {
        bb0 = *(const float4*)(b1 + g * 4);
        bb1 = *(const float4*)(b1 + 64 + g * 4);
    }
#pragma unroll
    for (int i = 0; i < 4; ++i) {
        int row = i0 + mr + i;
        if (row >= n) continue;
        float4 v0, v1;
        v0.x = __expf(2.f * (acc[i][0] + bb0.x));
        v0.y = __expf(2.f * (acc[i][1] + bb0.y));
        v0.z = __expf(2.f * (acc[i][2] + bb0.z));
        v0.w = __expf(2.f * (acc[i][3] + bb0.w));
        v1.x = __expf(2.f * (acc[i][4] + bb1.x));
        v1.y = __expf(2.f * (acc[i][5] + bb1.y));
        v1.z = __expf(2.f * (acc[i][6] + bb1.z));
        v1.w = __expf(2.f * (acc[i][7] + bb1.w));
        *(float4*)(outp + (size_t)row * F + g * 4) = v0;
        *(float4*)(outp + (size_t)row * F + 64 + g * 4) = v1;
    }
}

// ---------------------------------------------------------------------------
// Kernel B: row_ptr[v] = first edge index with dst >= v  (dst is sorted)
// ---------------------------------------------------------------------------
__global__ void rowptr_kernel(const int* __restrict__ dst,
                              int* __restrict__ row_ptr, int e, int n)
{
    int i = blockIdx.x * blockDim.x + threadIdx.x;
    if (i >= e) return;
    int d = dst[i];
    int prev = (i == 0) ? -1 : dst[i - 1];
    for (int v = prev + 1; v <= d; ++v) row_ptr[v] = i;
    if (i == e - 1) {
        for (int v = d + 1; v <= n; ++v) row_ptr[v] = e;
    }
}

// ---------------------------------------------------------------------------
// Kernel C v3: half-wave (32 lanes x float4) per edge, grid-stride.
// scores[e] = b2 + sum_f w2[f] * (1 - 2/(E_dst[dst][f]*E_src[src][f] + 1))
// 4 VALU per element (mul-add fused, rcp, fma, fma) vs ~14 for tanhf.
// ---------------------------------------------------------------------------
__global__ __launch_bounds__(256) void score_kernel(
    const float* __restrict__ e_dst, const float* __restrict__ e_src,
    const int* __restrict__ src, const int* __restrict__ dst,
    const float* __restrict__ w2, const float* __restrict__ b2,
    float* __restrict__ scores, int e)
{
    const int t = threadIdx.x;
    const int lane = t & 63;
    const int half = lane >> 5;
    const int fl = lane & 31;

    const float4 w = ((const float4*)w2)[fl];
    const float bb = b2[0];

    const int wid = (blockIdx.x * 256 + t) >> 6;
    const int nwaves = (gridDim.x * 256) >> 6;

    for (int base = wid * 2; base < e; base += nwaves * 2) {
        const int ei = base + half;
        int s = 0, d = 0;
        if (ei < e) { s = src[ei]; d = dst[ei]; }

        const float4 a = ((const float4*)(e_dst + (size_t)d * F))[fl];
        const float4 b = ((const float4*)(e_src + (size_t)s * F))[fl];

        float r, v = 0.f;
        r = __builtin_amdgcn_rcpf(fmaf(a.x, b.x, 1.f));
        v = fmaf(w.x, fmaf(-2.f, r, 1.f), v);
        r = __builtin_amdgcn_rcpf(fmaf(a.y, b.y, 1.f));
        v = fmaf(w.y, fmaf(-2.f, r, 1.f), v);
        r = __builtin_amdgcn_rcpf(fmaf(a.z, b.z, 1.f));
        v = fmaf(w.z, fmaf(-2.f, r, 1.f), v);
        r = __builtin_amdgcn_rcpf(fmaf(a.w, b.w, 1.f));
        v = fmaf(w.w, fmaf(-2.f, r, 1.f), v);

#pragma unroll
        for (int off = 16; off; off >>= 1) v += __shfl_xor(v, off, 64);

        if (fl == 0 && ei < e) scores[ei] = v + bb;
    }
}

// ---------------------------------------------------------------------------
// Kernel D v3: one 32-lane half-wave per node, float4 per lane (512B row in
// one VMEM instr). 8 nodes per 256-block. Fast path deg<=32 keeps scores in
// registers and broadcasts exp via shfl.
// ---------------------------------------------------------------------------
__global__ __launch_bounds__(256) void agg_kernel(
    const float* __restrict__ feat, const int* __restrict__ src,
    const int* __restrict__ row_ptr, const float* __restrict__ scores,
    float* __restrict__ neigh_out, int n)
{
    const int v = (int)((blockIdx.x * 256u + threadIdx.x) >> 5);
    const int fl = threadIdx.x & 31;
    const int sbase = threadIdx.x & 32;   // shfl offset of this half-wave
    if (v >= n) return;

    const int begin = row_ptr[v];
    const int end = row_ptr[v + 1];
    const int deg = end - begin;

    float4 acc = make_float4(0.f, 0.f, 0.f, 0.f);
    if (deg > 0) {
        if (deg <= 32) {
            float sc = (fl < deg) ? scores[begin + fl] : -INFINITY;
            int   sv = (fl < deg) ? src[begin + fl] : 0;
            float m = sc;
#pragma unroll
            for (int off = 16; off; off >>= 1) m = fmaxf(m, __shfl_xor(m, off, 64));
            float ex = (fl < deg) ? __expf(sc - m) : 0.f;
            float s = ex;
#pragma unroll
            for (int off = 16; off; off >>= 1) s += __shfl_xor(s, off, 64);
            const float inv = 1.f / s;

            for (int j = 0; j < deg; ++j) {
                const float wgt = __shfl(ex, sbase + j, 64);
                const int sr = __shfl(sv, sbase + j, 64);
                const float4 f = ((const float4*)(feat + (size_t)sr * F))[fl];
                acc.x = fmaf(wgt, f.x, acc.x);
                acc.y = fmaf(wgt, f.y, acc.y);
                acc.z = fmaf(wgt, f.z, acc.z);
                acc.w = fmaf(wgt, f.w, acc.w);
            }
            acc.x *= inv; acc.y *= inv; acc.z *= inv; acc.w *= inv;
        } else {
            float m = -INFINITY;
            for (int e2 = begin + fl; e2 < end; e2 += 32) m = fmaxf(m, scores[e2]);
#pragma unroll
            for (int off = 16; off; off >>= 1) m = fmaxf(m, __shfl_xor(m, off, 64));
            float s = 0.f;
            for (int e2 = begin + fl; e2 < end; e2 += 32) s += __expf(scores[e2] - m);
#pragma unroll
            for (int off = 16; off; off >>= 1) s += __shfl_xor(s, off, 64);
            const float inv = 1.f / s;

            for (int j = begin; j < end; ++j) {
                const float wgt = __expf(scores[j] - m);
                const int sr = src[j];
                const float4 f = ((const float4*)(feat + (size_t)sr * F))[fl];
                acc.x = fmaf(wgt, f.x, acc.x);
                acc.y = fmaf(wgt, f.y, acc.y);
                acc.z = fmaf(wgt, f.z, acc.z);
                acc.w = fmaf(wgt, f.w, acc.w);
            }
            acc.x *= inv; acc.y *= inv; acc.z *= inv; acc.w *= inv;
        }
    }
    ((float4*)(neigh_out + (size_t)v * F))[fl] = acc;
}

// ---------------------------------------------------------------------------
// Kernel E v3: register-tiled out = [feat|neigh] @ wf + bf.
// K=256 (k<128 from feat, k>=128 from neigh), BM=64, BN=128 (full OUT).
// ---------------------------------------------------------------------------
__global__ __launch_bounds__(256) void out_kernel(
    const float* __restrict__ feat, const float* __restrict__ neigh,
    const float* __restrict__ wf, const float* __restrict__ bf,
    float* __restrict__ out, int n)
{
    __shared__ float As[BK][BM];
    __shared__ float Bs[BK][BN];

    const int t  = threadIdx.x;
    const int i0 = blockIdx.x * BM;
    const int g  = t >> 4;
    const int mr = (t & 15) * 4;

    float acc[4][8];
#pragma unroll
    for (int i = 0; i < 4; ++i)
#pragma unroll
        for (int j = 0; j < 8; ++j) acc[i][j] = 0.f;

    for (int k0 = 0; k0 < 2 * F; k0 += BK) {
        const float* A = (k0 < F) ? feat : neigh;
        const int kc = k0 & (F - 1);
        {
            int row = t >> 3, c4 = (t & 7) * 4;
            float4 a = ((i0 + row) < n)
                ? *(const float4*)(A + (size_t)(i0 + row) * F + kc + c4)
                : make_float4(0.f, 0.f, 0.f, 0.f);
            As[c4 + 0][row] = a.x; As[c4 + 1][row] = a.y;
            As[c4 + 2][row] = a.z; As[c4 + 3][row] = a.w;
            row += 32;
            float4 b = ((i0 + row) < n)
                ? *(const float4*)(A + (size_t)(i0 + row) * F + kc + c4)
                : make_float4(0.f, 0.f, 0.f, 0.f);
            As[c4 + 0][row] = b.x; As[c4 + 1][row] = b.y;
            As[c4 + 2][row] = b.z; As[c4 + 3][row] = b.w;
        }
#pragma unroll
        for (int q = 0; q < 4; ++q) {
            int idx = t + 256 * q;
            int row = idx >> 5, c4 = (idx & 31) * 4;
            *(float4*)&Bs[row][c4] =
                *(const float4*)(wf + (size_t)(k0 + row) * OUT + c4);
        }
        __syncthreads();

#pragma unroll
        for (int k = 0; k < BK; ++k) {
            float4 a  = *(const float4*)&As[k][mr];
            float4 b0 = *(const float4*)&Bs[k][g * 4];
            float4 b1v = *(const float4*)&Bs[k][64 + g * 4];
            float av[4] = {a.x, a.y, a.z, a.w};
            float bv[8] = {b0.x, b0.y, b0.z, b0.w, b1v.x, b1v.y, b1v.z, b1v.w};
#pragma unroll
            for (int i = 0; i < 4; ++i)
#pragma unroll
                for (int j = 0; j < 8; ++j)
                    acc[i][j] = fmaf(av[i], bv[j], acc[i][j]);
        }
        __syncthreads();
    }

    const float4 bb0 = *(const float4*)(bf + g * 4);
    const float4 bb1 = *(const float4*)(bf + 64 + g * 4);
#pragma unroll
    for (int i = 0; i < 4; ++i) {
        int row = i0 + mr + i;
        if (row >= n) continue;
        float4 v0 = make_float4(acc[i][0] + bb0.x, acc[i][1] + bb0.y,
                                acc[i][2] + bb0.z, acc[i][3] + bb0.w);
        float4 v1 = make_float4(acc[i][4] + bb1.x, acc[i][5] + bb1.y,
                                acc[i][6] + bb1.z, acc[i][7] + bb1.w);
        *(float4*)(out + (size_t)row * OUT + g * 4) = v0;
        *(float4*)(out + (size_t)row * OUT + 64 + g * 4) = v1;
    }
}

// ---------------------------------------------------------------------------
extern "C" void kernel_launch(void* const* d_in, const int* in_sizes, int n_in,
                              void* d_out, int out_size, void* d_ws, size_t ws_size,
                              hipStream_t stream)
{
    const float* feat = (const float*)d_in[0];
    const int*   src  = (const int*)d_in[1];
    const int*   dst  = (const int*)d_in[2];
    const float* w1   = (const float*)d_in[3];
    const float* b1   = (const float*)d_in[4];
    const float* w2   = (const float*)d_in[5];
    const float* b2   = (const float*)d_in[6];
    const float* wf   = (const float*)d_in[7];
    const float* bf   = (const float*)d_in[8];
    float* out = (float*)d_out;

    const int n = in_sizes[0] / F;   // 40000
    const int e = in_sizes[1];       // 640000

    float* e_dst  = (float*)d_ws;
    float* e_src  = e_dst + (size_t)n * F;
    float* scores = e_src + (size_t)n * F;
    float* neigh  = scores + e;
    int*   row_ptr = (int*)(neigh + (size_t)n * F);

    proj_kernel<<<dim3((n + BM - 1) / BM, 2), 256, 0, stream>>>(
        feat, w1, b1, e_dst, e_src, n);
    rowptr_kernel<<<(e + 255) / 256, 256, 0, stream>>>(dst, row_ptr, e, n);
    score_kernel<<<4096, 256, 0, stream>>>(e_dst, e_src, src, dst,
                                           w2, b2, scores, e);
    agg_kernel<<<(n + 7) / 8, 256, 0, stream>>>(feat, src, row_ptr, scores, neigh, n);
    out_kernel<<<(n + BM - 1) / BM, 256, 0, stream>>>(feat, neigh, wf, bf, out, n);
}

// Round 5
// 252.678 us; speedup vs baseline: 1.8310x; 1.0666x over previous
//
#include <hip/hip_runtime.h>
#include <math.h>

#define F 128
#define OUT 128
#define BM 64
#define BN 128
#define BK 32

typedef unsigned short ushort_t;

__device__ __forceinline__ float bf2f(ushort_t u) {
    return __uint_as_float(((unsigned int)u) << 16);
}
__device__ __forceinline__ ushort_t f2bf(float f) {
    // round-to-nearest-even bf16 (values here are finite; NaN not expected)
    unsigned int x = __float_as_uint(f);
    unsigned int r = x + 0x7fffu + ((x >> 16) & 1u);
    return (ushort_t)(r >> 16);
}

// ---------------------------------------------------------------------------
// Kernel A: register-tiled GEMM, 256 threads, BM=64 x BN=128, TM=4 x TN=4+4.
// grid (n/BM, 2): h==0 -> e_dst = exp(2*(feat@w1[:F] + b1)) stored bf16
//                 h==1 -> e_src = exp(2*(feat@w1[F:]))      stored bf16
// (exp-form lets score_kernel use tanh(a+b) = 1 - 2/(Ea*Eb+1))
// ---------------------------------------------------------------------------
__global__ __launch_bounds__(256) void proj_kernel(
    const float* __restrict__ feat, const float* __restrict__ w1,
    const float* __restrict__ b1, ushort_t* __restrict__ e_dst,
    ushort_t* __restrict__ e_src, int n)
{
    __shared__ float As[BK][BM];   // transposed feat tile
    __shared__ float Bs[BK][BN];

    const int t  = threadIdx.x;
    const int i0 = blockIdx.x * BM;
    const int h  = blockIdx.y;
    const float* B = w1 + (size_t)h * F * F;

    const int g  = t >> 4;          // col group 0..15
    const int mr = (t & 15) * 4;    // row0 of thread tile

    float acc[4][8];
#pragma unroll
    for (int i = 0; i < 4; ++i)
#pragma unroll
        for (int j = 0; j < 8; ++j) acc[i][j] = 0.f;

    for (int k0 = 0; k0 < F; k0 += BK) {
        {
            int row = t >> 3, c4 = (t & 7) * 4;
            float4 a = ((i0 + row) < n)
                ? *(const float4*)(feat + (size_t)(i0 + row) * F + k0 + c4)
                : make_float4(0.f, 0.f, 0.f, 0.f);
            As[c4 + 0][row] = a.x; As[c4 + 1][row] = a.y;
            As[c4 + 2][row] = a.z; As[c4 + 3][row] = a.w;
            row += 32;
            float4 b = ((i0 + row) < n)
                ? *(const float4*)(feat + (size_t)(i0 + row) * F + k0 + c4)
                : make_float4(0.f, 0.f, 0.f, 0.f);
            As[c4 + 0][row] = b.x; As[c4 + 1][row] = b.y;
            As[c4 + 2][row] = b.z; As[c4 + 3][row] = b.w;
        }
#pragma unroll
        for (int q = 0; q < 4; ++q) {
            int idx = t + 256 * q;
            int row = idx >> 5, c4 = (idx & 31) * 4;
            *(float4*)&Bs[row][c4] =
                *(const float4*)(B + (size_t)(k0 + row) * F + c4);
        }
        __syncthreads();

#pragma unroll
        for (int k = 0; k < BK; ++k) {
            float4 a  = *(const float4*)&As[k][mr];
            float4 b0 = *(const float4*)&Bs[k][g * 4];
            float4 b1v = *(const float4*)&Bs[k][64 + g * 4];
            float av[4] = {a.x, a.y, a.z, a.w};
            float bv[8] = {b0.x, b0.y, b0.z, b0.w, b1v.x, b1v.y, b1v.z, b1v.w};
#pragma unroll
            for (int i = 0; i < 4; ++i)
#pragma unroll
                for (int j = 0; j < 8; ++j)
                    acc[i][j] = fmaf(av[i], bv[j], acc[i][j]);
        }
        __syncthreads();
    }

    ushort_t* outp = (h == 0) ? e_dst : e_src;
    float4 bb0 = make_float4(0.f, 0.f, 0.f, 0.f), bb1 = bb0;
    if (h == 0) {
        bb0 = *(const float4*)(b1 + g * 4);
        bb1 = *(const float4*)(b1 + 64 + g * 4);
    }
#pragma unroll
    for (int i = 0; i < 4; ++i) {
        int row = i0 + mr + i;
        if (row >= n) continue;
        ushort4 u0, u1;
        u0.x = f2bf(__expf(2.f * (acc[i][0] + bb0.x)));
        u0.y = f2bf(__expf(2.f * (acc[i][1] + bb0.y)));
        u0.z = f2bf(__expf(2.f * (acc[i][2] + bb0.z)));
        u0.w = f2bf(__expf(2.f * (acc[i][3] + bb0.w)));
        u1.x = f2bf(__expf(2.f * (acc[i][4] + bb1.x)));
        u1.y = f2bf(__expf(2.f * (acc[i][5] + bb1.y)));
        u1.z = f2bf(__expf(2.f * (acc[i][6] + bb1.z)));
        u1.w = f2bf(__expf(2.f * (acc[i][7] + bb1.w)));
        *(ushort4*)(outp + (size_t)row * F + g * 4) = u0;
        *(ushort4*)(outp + (size_t)row * F + 64 + g * 4) = u1;
    }
}

// ---------------------------------------------------------------------------
// Kernel A2: cast feat -> bf16 (for agg gathers). 8 elems/thread.
// ---------------------------------------------------------------------------
__global__ __launch_bounds__(256) void cast_kernel(
    const float* __restrict__ feat, ushort_t* __restrict__ feat_bf, int total8)
{
    int i = blockIdx.x * 256 + threadIdx.x;
    if (i >= total8) return;
    const float4 a = ((const float4*)feat)[i * 2];
    const float4 b = ((const float4*)feat)[i * 2 + 1];
    ushort4 u0, u1;
    u0.x = f2bf(a.x); u0.y = f2bf(a.y); u0.z = f2bf(a.z); u0.w = f2bf(a.w);
    u1.x = f2bf(b.x); u1.y = f2bf(b.y); u1.z = f2bf(b.z); u1.w = f2bf(b.w);
    ((ushort4*)feat_bf)[i * 2] = u0;
    ((ushort4*)feat_bf)[i * 2 + 1] = u1;
}

// ---------------------------------------------------------------------------
// Kernel B: row_ptr[v] = first edge index with dst >= v  (dst is sorted)
// ---------------------------------------------------------------------------
__global__ void rowptr_kernel(const int* __restrict__ dst,
                              int* __restrict__ row_ptr, int e, int n)
{
    int i = blockIdx.x * blockDim.x + threadIdx.x;
    if (i >= e) return;
    int d = dst[i];
    int prev = (i == 0) ? -1 : dst[i - 1];
    for (int v = prev + 1; v <= d; ++v) row_ptr[v] = i;
    if (i == e - 1) {
        for (int v = d + 1; v <= n; ++v) row_ptr[v] = e;
    }
}

// ---------------------------------------------------------------------------
// Kernel C v4: half-wave (32 lanes x 4 feats) per edge; each wave owns a
// chunk of 16 consecutive edges (sorted dst -> e_dst rows L1-hot).
// scores[e] = b2 + sum_f w2[f] * (1 - 2/(E_dst[dst][f]*E_src[src][f] + 1))
// E tables are bf16 (256B rows): halves gather bytes, doubles L2 hit rate.
// ---------------------------------------------------------------------------
__global__ __launch_bounds__(256) void score_kernel(
    const ushort_t* __restrict__ e_dst, const ushort_t* __restrict__ e_src,
    const int* __restrict__ src, const int* __restrict__ dst,
    const float* __restrict__ w2, const float* __restrict__ b2,
    float* __restrict__ scores, int e)
{
    const int t = threadIdx.x;
    const int lane = t & 63;
    const int half = lane >> 5;
    const int fl = lane & 31;

    const float4 w = ((const float4*)w2)[fl];
    const float bb = b2[0];

    const int wid = (blockIdx.x * 256 + t) >> 6;
    const int nwaves = (gridDim.x * 256) >> 6;

    for (int base = wid * 16; base < e; base += nwaves * 16) {
#pragma unroll
        for (int j = 0; j < 8; ++j) {
            const int ei = base + j * 2 + half;
            int s = 0, d = 0;
            if (ei < e) { s = src[ei]; d = dst[ei]; }

            const ushort4 ua = ((const ushort4*)(e_dst + (size_t)d * F))[fl];
            const ushort4 ub = ((const ushort4*)(e_src + (size_t)s * F))[fl];

            float r, v = 0.f;
            r = __builtin_amdgcn_rcpf(fmaf(bf2f(ua.x), bf2f(ub.x), 1.f));
            v = fmaf(w.x, fmaf(-2.f, r, 1.f), v);
            r = __builtin_amdgcn_rcpf(fmaf(bf2f(ua.y), bf2f(ub.y), 1.f));
            v = fmaf(w.y, fmaf(-2.f, r, 1.f), v);
            r = __builtin_amdgcn_rcpf(fmaf(bf2f(ua.z), bf2f(ub.z), 1.f));
            v = fmaf(w.z, fmaf(-2.f, r, 1.f), v);
            r = __builtin_amdgcn_rcpf(fmaf(bf2f(ua.w), bf2f(ub.w), 1.f));
            v = fmaf(w.w, fmaf(-2.f, r, 1.f), v);

#pragma unroll
            for (int off = 16; off; off >>= 1) v += __shfl_xor(v, off, 64);

            if (fl == 0 && ei < e) scores[ei] = v + bb;
        }
    }
}

// ---------------------------------------------------------------------------
// Kernel D v4: one 32-lane half-wave per node; bf16 feat gathers (256B rows,
// one dwordx2 per lane per row). Fast path deg<=32 broadcasts exp via shfl.
// ---------------------------------------------------------------------------
__global__ __launch_bounds__(256) void agg_kernel(
    const ushort_t* __restrict__ feat_bf, const int* __restrict__ src,
    const int* __restrict__ row_ptr, const float* __restrict__ scores,
    float* __restrict__ neigh_out, int n)
{
    const int v = (int)((blockIdx.x * 256u + threadIdx.x) >> 5);
    const int fl = threadIdx.x & 31;
    const int sbase = threadIdx.x & 32;   // shfl offset of this half-wave
    if (v >= n) return;

    const int begin = row_ptr[v];
    const int end = row_ptr[v + 1];
    const int deg = end - begin;

    float4 acc = make_float4(0.f, 0.f, 0.f, 0.f);
    if (deg > 0) {
        if (deg <= 32) {
            float sc = (fl < deg) ? scores[begin + fl] : -INFINITY;
            int   sv = (fl < deg) ? src[begin + fl] : 0;
            float m = sc;
#pragma unroll
            for (int off = 16; off; off >>= 1) m = fmaxf(m, __shfl_xor(m, off, 64));
            float ex = (fl < deg) ? __expf(sc - m) : 0.f;
            float s = ex;
#pragma unroll
            for (int off = 16; off; off >>= 1) s += __shfl_xor(s, off, 64);
            const float inv = 1.f / s;

            for (int j = 0; j < deg; ++j) {
                const float wgt = __shfl(ex, sbase + j, 64);
                const int sr = __shfl(sv, sbase + j, 64);
                const ushort4 f = ((const ushort4*)(feat_bf + (size_t)sr * F))[fl];
                acc.x = fmaf(wgt, bf2f(f.x), acc.x);
                acc.y = fmaf(wgt, bf2f(f.y), acc.y);
                acc.z = fmaf(wgt, bf2f(f.z), acc.z);
                acc.w = fmaf(wgt, bf2f(f.w), acc.w);
            }
            acc.x *= inv; acc.y *= inv; acc.z *= inv; acc.w *= inv;
        } else {
            float m = -INFINITY;
            for (int e2 = begin + fl; e2 < end; e2 += 32) m = fmaxf(m, scores[e2]);
#pragma unroll
            for (int off = 16; off; off >>= 1) m = fmaxf(m, __shfl_xor(m, off, 64));
            float s = 0.f;
            for (int e2 = begin + fl; e2 < end; e2 += 32) s += __expf(scores[e2] - m);
#pragma unroll
            for (int off = 16; off; off >>= 1) s += __shfl_xor(s, off, 64);
            const float inv = 1.f / s;

            for (int j = begin; j < end; ++j) {
                const float wgt = __expf(scores[j] - m);
                const int sr = src[j];
                const ushort4 f = ((const ushort4*)(feat_bf + (size_t)sr * F))[fl];
                acc.x = fmaf(wgt, bf2f(f.x), acc.x);
                acc.y = fmaf(wgt, bf2f(f.y), acc.y);
                acc.z = fmaf(wgt, bf2f(f.z), acc.z);
                acc.w = fmaf(wgt, bf2f(f.w), acc.w);
            }
            acc.x *= inv; acc.y *= inv; acc.z *= inv; acc.w *= inv;
        }
    }
    ((float4*)(neigh_out + (size_t)v * F))[fl] = acc;
}

// ---------------------------------------------------------------------------
// Kernel E: register-tiled out = [feat|neigh] @ wf + bf.  (fp32)
// ---------------------------------------------------------------------------
__global__ __launch_bounds__(256) void out_kernel(
    const float* __restrict__ feat, const float* __restrict__ neigh,
    const float* __restrict__ wf, const float* __restrict__ bf,
    float* __restrict__ out, int n)
{
    __shared__ float As[BK][BM];
    __shared__ float Bs[BK][BN];

    const int t  = threadIdx.x;
    const int i0 = blockIdx.x * BM;
    const int g  = t >> 4;
    const int mr = (t & 15) * 4;

    float acc[4][8];
#pragma unroll
    for (int i = 0; i < 4; ++i)
#pragma unroll
        for (int j = 0; j < 8; ++j) acc[i][j] = 0.f;

    for (int k0 = 0; k0 < 2 * F; k0 += BK) {
        const float* A = (k0 < F) ? feat : neigh;
        const int kc = k0 & (F - 1);
        {
            int row = t >> 3, c4 = (t & 7) * 4;
            float4 a = ((i0 + row) < n)
                ? *(const float4*)(A + (size_t)(i0 + row) * F + kc + c4)
                : make_float4(0.f, 0.f, 0.f, 0.f);
            As[c4 + 0][row] = a.x; As[c4 + 1][row] = a.y;
            As[c4 + 2][row] = a.z; As[c4 + 3][row] = a.w;
            row += 32;
            float4 b = ((i0 + row) < n)
                ? *(const float4*)(A + (size_t)(i0 + row) * F + kc + c4)
                : make_float4(0.f, 0.f, 0.f, 0.f);
            As[c4 + 0][row] = b.x; As[c4 + 1][row] = b.y;
            As[c4 + 2][row] = b.z; As[c4 + 3][row] = b.w;
        }
#pragma unroll
        for (int q = 0; q < 4; ++q) {
            int idx = t + 256 * q;
            int row = idx >> 5, c4 = (idx & 31) * 4;
            *(float4*)&Bs[row][c4] =
                *(const float4*)(wf + (size_t)(k0 + row) * OUT + c4);
        }
        __syncthreads();

#pragma unroll
        for (int k = 0; k < BK; ++k) {
            float4 a  = *(const float4*)&As[k][mr];
            float4 b0 = *(const float4*)&Bs[k][g * 4];
            float4 b1v = *(const float4*)&Bs[k][64 + g * 4];
            float av[4] = {a.x, a.y, a.z, a.w};
            float bv[8] = {b0.x, b0.y, b0.z, b0.w, b1v.x, b1v.y, b1v.z, b1v.w};
#pragma unroll
            for (int i = 0; i < 4; ++i)
#pragma unroll
                for (int j = 0; j < 8; ++j)
                    acc[i][j] = fmaf(av[i], bv[j], acc[i][j]);
        }
        __syncthreads();
    }

    const float4 bb0 = *(const float4*)(bf + g * 4);
    const float4 bb1 = *(const float4*)(bf + 64 + g * 4);
#pragma unroll
    for (int i = 0; i < 4; ++i) {
        int row = i0 + mr + i;
        if (row >= n) continue;
        float4 v0 = make_float4(acc[i][0] + bb0.x, acc[i][1] + bb0.y,
                                acc[i][2] + bb0.z, acc[i][3] + bb0.w);
        float4 v1 = make_float4(acc[i][4] + bb1.x, acc[i][5] + bb1.y,
                                acc[i][6] + bb1.z, acc[i][7] + bb1.w);
        *(float4*)(out + (size_t)row * OUT + g * 4) = v0;
        *(float4*)(out + (size_t)row * OUT + 64 + g * 4) = v1;
    }
}

// ---------------------------------------------------------------------------
extern "C" void kernel_launch(void* const* d_in, const int* in_sizes, int n_in,
                              void* d_out, int out_size, void* d_ws, size_t ws_size,
                              hipStream_t stream)
{
    const float* feat = (const float*)d_in[0];
    const int*   src  = (const int*)d_in[1];
    const int*   dst  = (const int*)d_in[2];
    const float* w1   = (const float*)d_in[3];
    const float* b1   = (const float*)d_in[4];
    const float* w2   = (const float*)d_in[5];
    const float* b2   = (const float*)d_in[6];
    const float* wf   = (const float*)d_in[7];
    const float* bf   = (const float*)d_in[8];
    float* out = (float*)d_out;

    const int n = in_sizes[0] / F;   // 40000
    const int e = in_sizes[1];       // 640000

    float* scores  = (float*)d_ws;                        // E
    float* neigh   = scores + e;                          // N*F
    ushort_t* e_dst = (ushort_t*)(neigh + (size_t)n * F); // N*F bf16
    ushort_t* e_src = e_dst + (size_t)n * F;              // N*F bf16
    ushort_t* feat_bf = e_src + (size_t)n * F;            // N*F bf16
    int* row_ptr = (int*)(feat_bf + (size_t)n * F);       // N+1

    proj_kernel<<<dim3((n + BM - 1) / BM, 2), 256, 0, stream>>>(
        feat, w1, b1, e_dst, e_src, n);
    cast_kernel<<<(n * F / 8 + 255) / 256, 256, 0, stream>>>(
        feat, feat_bf, n * F / 8);
    rowptr_kernel<<<(e + 255) / 256, 256, 0, stream>>>(dst, row_ptr, e, n);
    score_kernel<<<4096, 256, 0, stream>>>(e_dst, e_src, src, dst,
                                           w2, b2, scores, e);
    agg_kernel<<<(n + 7) / 8, 256, 0, stream>>>(feat_bf, src, row_ptr, scores,
                                                neigh, n);
    out_kernel<<<(n + BM - 1) / BM, 256, 0, stream>>>(feat, neigh, wf, bf, out, n);
}

// Round 6
// 219.773 us; speedup vs baseline: 2.1051x; 1.1497x over previous
//
#include <hip/hip_runtime.h>
#include <math.h>

#define F 128
#define OUT 128
#define BM 64
#define BN 128
#define BK 32

typedef unsigned short ushort_t;

__device__ __forceinline__ float bf_lo(unsigned int u) {
    return __uint_as_float(u << 16);
}
__device__ __forceinline__ float bf_hi(unsigned int u) {
    return __uint_as_float(u & 0xffff0000u);
}
__device__ __forceinline__ ushort_t f2bf(float f) {
    unsigned int x = __float_as_uint(f);
    unsigned int r = x + 0x7fffu + ((x >> 16) & 1u);
    return (ushort_t)(r >> 16);
}

// ---------------------------------------------------------------------------
// Kernel A: register-tiled GEMM, BM=64 x BN=128, TM=4 x TN=4+4.
// h==0 -> e_dst[v][f]    = bf16(exp(2*(feat@w1[:F] + b1)))   (stride 128)
// h==1 -> srcpack[v][f]  = bf16(exp(2*(feat@w1[F:])))        (stride 256,
//         lower half of the interleaved [e_src | feat] row)
// ---------------------------------------------------------------------------
__global__ __launch_bounds__(256) void proj_kernel(
    const float* __restrict__ feat, const float* __restrict__ w1,
    const float* __restrict__ b1, ushort_t* __restrict__ e_dst,
    ushort_t* __restrict__ srcpack, int n)
{
    __shared__ float As[BK][BM];
    __shared__ float Bs[BK][BN];

    const int t  = threadIdx.x;
    const int i0 = blockIdx.x * BM;
    const int h  = blockIdx.y;
    const float* B = w1 + (size_t)h * F * F;

    const int g  = t >> 4;
    const int mr = (t & 15) * 4;

    float acc[4][8];
#pragma unroll
    for (int i = 0; i < 4; ++i)
#pragma unroll
        for (int j = 0; j < 8; ++j) acc[i][j] = 0.f;

    for (int k0 = 0; k0 < F; k0 += BK) {
        {
            int row = t >> 3, c4 = (t & 7) * 4;
            float4 a = ((i0 + row) < n)
                ? *(const float4*)(feat + (size_t)(i0 + row) * F + k0 + c4)
                : make_float4(0.f, 0.f, 0.f, 0.f);
            As[c4 + 0][row] = a.x; As[c4 + 1][row] = a.y;
            As[c4 + 2][row] = a.z; As[c4 + 3][row] = a.w;
            row += 32;
            float4 b = ((i0 + row) < n)
                ? *(const float4*)(feat + (size_t)(i0 + row) * F + k0 + c4)
                : make_float4(0.f, 0.f, 0.f, 0.f);
            As[c4 + 0][row] = b.x; As[c4 + 1][row] = b.y;
            As[c4 + 2][row] = b.z; As[c4 + 3][row] = b.w;
        }
#pragma unroll
        for (int q = 0; q < 4; ++q) {
            int idx = t + 256 * q;
            int row = idx >> 5, c4 = (idx & 31) * 4;
            *(float4*)&Bs[row][c4] =
                *(const float4*)(B + (size_t)(k0 + row) * F + c4);
        }
        __syncthreads();

#pragma unroll
        for (int k = 0; k < BK; ++k) {
            float4 a  = *(const float4*)&As[k][mr];
            float4 b0 = *(const float4*)&Bs[k][g * 4];
            float4 b1v = *(const float4*)&Bs[k][64 + g * 4];
            float av[4] = {a.x, a.y, a.z, a.w};
            float bv[8] = {b0.x, b0.y, b0.z, b0.w, b1v.x, b1v.y, b1v.z, b1v.w};
#pragma unroll
            for (int i = 0; i < 4; ++i)
#pragma unroll
                for (int j = 0; j < 8; ++j)
                    acc[i][j] = fmaf(av[i], bv[j], acc[i][j]);
        }
        __syncthreads();
    }

    ushort_t* outp = (h == 0) ? e_dst : srcpack;
    const size_t stride = (h == 0) ? 128 : 256;
    float4 bb0 = make_float4(0.f, 0.f, 0.f, 0.f), bb1 = bb0;
    if (h == 0) {
        bb0 = *(const float4*)(b1 + g * 4);
        bb1 = *(const float4*)(b1 + 64 + g * 4);
    }
#pragma unroll
    for (int i = 0; i < 4; ++i) {
        int row = i0 + mr + i;
        if (row >= n) continue;
        ushort4 u0, u1;
        u0.x = f2bf(__expf(2.f * (acc[i][0] + bb0.x)));
        u0.y = f2bf(__expf(2.f * (acc[i][1] + bb0.y)));
        u0.z = f2bf(__expf(2.f * (acc[i][2] + bb0.z)));
        u0.w = f2bf(__expf(2.f * (acc[i][3] + bb0.w)));
        u1.x = f2bf(__expf(2.f * (acc[i][4] + bb1.x)));
        u1.y = f2bf(__expf(2.f * (acc[i][5] + bb1.y)));
        u1.z = f2bf(__expf(2.f * (acc[i][6] + bb1.z)));
        u1.w = f2bf(__expf(2.f * (acc[i][7] + bb1.w)));
        *(ushort4*)(outp + (size_t)row * stride + g * 4) = u0;
        *(ushort4*)(outp + (size_t)row * stride + 64 + g * 4) = u1;
    }
}

// ---------------------------------------------------------------------------
// Kernel A2: pack feat (bf16) into the upper half of srcpack rows.
// ---------------------------------------------------------------------------
__global__ __launch_bounds__(256) void pack_kernel(
    const float* __restrict__ feat, ushort_t* __restrict__ srcpack, int n)
{
    int i = blockIdx.x * 256 + threadIdx.x;   // one thread per 8 elements
    if (i >= n * 16) return;
    int row = i >> 4, c = (i & 15) * 8;
    const float4 a = *(const float4*)(feat + (size_t)row * F + c);
    const float4 b = *(const float4*)(feat + (size_t)row * F + c + 4);
    ushort4 u0, u1;
    u0.x = f2bf(a.x); u0.y = f2bf(a.y); u0.z = f2bf(a.z); u0.w = f2bf(a.w);
    u1.x = f2bf(b.x); u1.y = f2bf(b.y); u1.z = f2bf(b.z); u1.w = f2bf(b.w);
    *(ushort4*)(srcpack + (size_t)row * 256 + 128 + c) = u0;
    *(ushort4*)(srcpack + (size_t)row * 256 + 128 + c + 4) = u1;
}

// ---------------------------------------------------------------------------
// Kernel B: row_ptr[v] = first edge index with dst >= v  (dst is sorted)
// ---------------------------------------------------------------------------
__global__ void rowptr_kernel(const int* __restrict__ dst,
                              int* __restrict__ row_ptr, int e, int n)
{
    int i = blockIdx.x * blockDim.x + threadIdx.x;
    if (i >= e) return;
    int d = dst[i];
    int prev = (i == 0) ? -1 : dst[i - 1];
    for (int v = prev + 1; v <= d; ++v) row_ptr[v] = i;
    if (i == e - 1) {
        for (int v = d + 1; v <= n; ++v) row_ptr[v] = e;
    }
}

// ---------------------------------------------------------------------------
// Kernel C (fused score+softmax+aggregate): one 32-lane half-wave per node.
// Lanes 0..15 = score lanes (e_src chunk of the packed row); lanes 16..31 =
// agg lanes (feat chunk). One dwordx4 gather per edge serves both. Online
// softmax (rescale only when the running max changes). Scores never hit
// memory; e_dst row loaded once per node.
//   score = b2 + sum_f w2_f * (1 - 2/(Ea_f*Eb_f+1)) = c0 - 2*sum_f w2_f*r_f
// ---------------------------------------------------------------------------
__global__ __launch_bounds__(256) void fused_kernel(
    const ushort_t* __restrict__ e_dst, const ushort_t* __restrict__ srcpack,
    const int* __restrict__ src, const int* __restrict__ row_ptr,
    const float* __restrict__ w2, const float* __restrict__ b2,
    float* __restrict__ neigh_out, int n)
{
    const int v = (int)((blockIdx.x * 256u + threadIdx.x) >> 5);
    const int fl = threadIdx.x & 31;
    const int sbase = threadIdx.x & 32;     // shfl base of this half-wave
    const bool is_score = (fl < 16);

    // per-thread w2 chunk and c0 = b2 + sum(w2)
    float w[8];
#pragma unroll
    for (int i = 0; i < 8; ++i) w[i] = 0.f;
    if (is_score) {
        float4 wa = ((const float4*)w2)[2 * fl];
        float4 wb = ((const float4*)w2)[2 * fl + 1];
        w[0] = wa.x; w[1] = wa.y; w[2] = wa.z; w[3] = wa.w;
        w[4] = wb.x; w[5] = wb.y; w[6] = wb.z; w[7] = wb.w;
    }
    float v0 = w[0] + w[1] + w[2] + w[3] + w[4] + w[5] + w[6] + w[7];
#pragma unroll
    for (int off = 16; off; off >>= 1) v0 += __shfl_xor(v0, off, 64);
    const float c0 = v0 + b2[0];

    if (v >= n) return;

    const int begin = row_ptr[v];
    const int end = row_ptr[v + 1];

    // preload e_dst row chunk (score lanes only)
    float ea[8];
#pragma unroll
    for (int i = 0; i < 8; ++i) ea[i] = 0.f;
    if (is_score) {
        uint4 ud = ((const uint4*)(e_dst + (size_t)v * F))[fl];
        ea[0] = bf_lo(ud.x); ea[1] = bf_hi(ud.x);
        ea[2] = bf_lo(ud.y); ea[3] = bf_hi(ud.y);
        ea[4] = bf_lo(ud.z); ea[5] = bf_hi(ud.z);
        ea[6] = bf_lo(ud.w); ea[7] = bf_hi(ud.w);
    }

    float m = -INFINITY, s = 0.f;
    float acc[8];
#pragma unroll
    for (int i = 0; i < 8; ++i) acc[i] = 0.f;

    for (int cb = begin; cb < end; cb += 32) {
        const int clen = min(32, end - cb);
        const int idx = cb + fl;
        const int sv = (fl < clen) ? src[idx] : 0;

        int sj = __shfl(sv, sbase, 64);
        uint4 cur = ((const uint4*)(srcpack + (size_t)sj * 256))[fl];

        for (int jj = 0; jj < clen; ++jj) {
            uint4 nxt = cur;
            if (jj + 1 < clen) {
                int sn = __shfl(sv, sbase + jj + 1, 64);
                nxt = ((const uint4*)(srcpack + (size_t)sn * 256))[fl];
            }

            // unpack 8 bf16 -> float (e_src chunk for score lanes,
            // feat chunk for agg lanes)
            float f0 = bf_lo(cur.x), f1 = bf_hi(cur.x);
            float f2 = bf_lo(cur.y), f3 = bf_hi(cur.y);
            float f4 = bf_lo(cur.z), f5 = bf_hi(cur.z);
            float f6 = bf_lo(cur.w), f7 = bf_hi(cur.w);

            float pv = 0.f;
            if (is_score) {
                float r;
                r = __builtin_amdgcn_rcpf(fmaf(ea[0], f0, 1.f)); pv = fmaf(w[0], r, pv);
                r = __builtin_amdgcn_rcpf(fmaf(ea[1], f1, 1.f)); pv = fmaf(w[1], r, pv);
                r = __builtin_amdgcn_rcpf(fmaf(ea[2], f2, 1.f)); pv = fmaf(w[2], r, pv);
                r = __builtin_amdgcn_rcpf(fmaf(ea[3], f3, 1.f)); pv = fmaf(w[3], r, pv);
                r = __builtin_amdgcn_rcpf(fmaf(ea[4], f4, 1.f)); pv = fmaf(w[4], r, pv);
                r = __builtin_amdgcn_rcpf(fmaf(ea[5], f5, 1.f)); pv = fmaf(w[5], r, pv);
                r = __builtin_amdgcn_rcpf(fmaf(ea[6], f6, 1.f)); pv = fmaf(w[6], r, pv);
                r = __builtin_amdgcn_rcpf(fmaf(ea[7], f7, 1.f)); pv = fmaf(w[7], r, pv);
            }
#pragma unroll
            for (int off = 16; off; off >>= 1) pv += __shfl_xor(pv, off, 64);

            const float sc = c0 - 2.f * pv;    // uniform across half-wave
            const float mold = m;
            m = fmaxf(m, sc);
            const float wgt = __expf(sc - m);
            if (sc > mold) {                   // max changed: rescale (rare)
                const float scale = __expf(mold - m);
                s *= scale;
#pragma unroll
                for (int i = 0; i < 8; ++i) acc[i] *= scale;
            }
            s += wgt;
            if (!is_score) {
                acc[0] = fmaf(wgt, f0, acc[0]);
                acc[1] = fmaf(wgt, f1, acc[1]);
                acc[2] = fmaf(wgt, f2, acc[2]);
                acc[3] = fmaf(wgt, f3, acc[3]);
                acc[4] = fmaf(wgt, f4, acc[4]);
                acc[5] = fmaf(wgt, f5, acc[5]);
                acc[6] = fmaf(wgt, f6, acc[6]);
                acc[7] = fmaf(wgt, f7, acc[7]);
            }
            cur = nxt;
        }
    }

    if (!is_score) {
        const float inv = (end > begin) ? 1.f / s : 0.f;
        float4 o0 = make_float4(acc[0] * inv, acc[1] * inv,
                                acc[2] * inv, acc[3] * inv);
        float4 o1 = make_float4(acc[4] * inv, acc[5] * inv,
                                acc[6] * inv, acc[7] * inv);
        float* row = neigh_out + (size_t)v * F + (fl - 16) * 8;
        *(float4*)row = o0;
        *(float4*)(row + 4) = o1;
    }
}

// ---------------------------------------------------------------------------
// Kernel E: register-tiled out = [feat|neigh] @ wf + bf.  (fp32)
// ---------------------------------------------------------------------------
__global__ __launch_bounds__(256) void out_kernel(
    const float* __restrict__ feat, const float* __restrict__ neigh,
    const float* __restrict__ wf, const float* __restrict__ bf,
    float* __restrict__ out, int n)
{
    __shared__ float As[BK][BM];
    __shared__ float Bs[BK][BN];

    const int t  = threadIdx.x;
    const int i0 = blockIdx.x * BM;
    const int g  = t >> 4;
    const int mr = (t & 15) * 4;

    float acc[4][8];
#pragma unroll
    for (int i = 0; i < 4; ++i)
#pragma unroll
        for (int j = 0; j < 8; ++j) acc[i][j] = 0.f;

    for (int k0 = 0; k0 < 2 * F; k0 += BK) {
        const float* A = (k0 < F) ? feat : neigh;
        const int kc = k0 & (F - 1);
        {
            int row = t >> 3, c4 = (t & 7) * 4;
            float4 a = ((i0 + row) < n)
                ? *(const float4*)(A + (size_t)(i0 + row) * F + kc + c4)
                : make_float4(0.f, 0.f, 0.f, 0.f);
            As[c4 + 0][row] = a.x; As[c4 + 1][row] = a.y;
            As[c4 + 2][row] = a.z; As[c4 + 3][row] = a.w;
            row += 32;
            float4 b = ((i0 + row) < n)
                ? *(const float4*)(A + (size_t)(i0 + row) * F + kc + c4)
                : make_float4(0.f, 0.f, 0.f, 0.f);
            As[c4 + 0][row] = b.x; As[c4 + 1][row] = b.y;
            As[c4 + 2][row] = b.z; As[c4 + 3][row] = b.w;
        }
#pragma unroll
        for (int q = 0; q < 4; ++q) {
            int idx = t + 256 * q;
            int row = idx >> 5, c4 = (idx & 31) * 4;
            *(float4*)&Bs[row][c4] =
                *(const float4*)(wf + (size_t)(k0 + row) * OUT + c4);
        }
        __syncthreads();

#pragma unroll
        for (int k = 0; k < BK; ++k) {
            float4 a  = *(const float4*)&As[k][mr];
            float4 b0 = *(const float4*)&Bs[k][g * 4];
            float4 b1v = *(const float4*)&Bs[k][64 + g * 4];
            float av[4] = {a.x, a.y, a.z, a.w};
            float bv[8] = {b0.x, b0.y, b0.z, b0.w, b1v.x, b1v.y, b1v.z, b1v.w};
#pragma unroll
            for (int i = 0; i < 4; ++i)
#pragma unroll
                for (int j = 0; j < 8; ++j)
                    acc[i][j] = fmaf(av[i], bv[j], acc[i][j]);
        }
        __syncthreads();
    }

    const float4 bb0 = *(const float4*)(bf + g * 4);
    const float4 bb1 = *(const float4*)(bf + 64 + g * 4);
#pragma unroll
    for (int i = 0; i < 4; ++i) {
        int row = i0 + mr + i;
        if (row >= n) continue;
        float4 v0 = make_float4(acc[i][0] + bb0.x, acc[i][1] + bb0.y,
                                acc[i][2] + bb0.z, acc[i][3] + bb0.w);
        float4 v1 = make_float4(acc[i][4] + bb1.x, acc[i][5] + bb1.y,
                                acc[i][6] + bb1.z, acc[i][7] + bb1.w);
        *(float4*)(out + (size_t)row * OUT + g * 4) = v0;
        *(float4*)(out + (size_t)row * OUT + 64 + g * 4) = v1;
    }
}

// ---------------------------------------------------------------------------
extern "C" void kernel_launch(void* const* d_in, const int* in_sizes, int n_in,
                              void* d_out, int out_size, void* d_ws, size_t ws_size,
                              hipStream_t stream)
{
    const float* feat = (const float*)d_in[0];
    const int*   src  = (const int*)d_in[1];
    const int*   dst  = (const int*)d_in[2];
    const float* w1   = (const float*)d_in[3];
    const float* b1   = (const float*)d_in[4];
    const float* w2   = (const float*)d_in[5];
    const float* b2   = (const float*)d_in[6];
    const float* wf   = (const float*)d_in[7];
    const float* bf   = (const float*)d_in[8];
    float* out = (float*)d_out;

    const int n = in_sizes[0] / F;   // 40000
    const int e = in_sizes[1];       // 640000

    float* neigh = (float*)d_ws;                          // n*F fp32
    ushort_t* e_dst = (ushort_t*)(neigh + (size_t)n * F); // n*128 bf16
    ushort_t* srcpack = e_dst + (size_t)n * F;            // n*256 bf16
    int* row_ptr = (int*)(srcpack + (size_t)n * 256);     // n+1

    proj_kernel<<<dim3((n + BM - 1) / BM, 2), 256, 0, stream>>>(
        feat, w1, b1, e_dst, srcpack, n);
    pack_kernel<<<(n * 16 + 255) / 256, 256, 0, stream>>>(feat, srcpack, n);
    rowptr_kernel<<<(e + 255) / 256, 256, 0, stream>>>(dst, row_ptr, e, n);
    fused_kernel<<<(n + 7) / 8, 256, 0, stream>>>(
        e_dst, srcpack, src, row_ptr, w2, b2, neigh, n);
    out_kernel<<<(n + BM - 1) / BM, 256, 0, stream>>>(feat, neigh, wf, bf, out, n);
}

// Round 7
// 178.868 us; speedup vs baseline: 2.5865x; 1.2287x over previous
//
#include <hip/hip_runtime.h>
#include <math.h>

#define F 128
#define OUT 128

typedef unsigned short ushort_t;
typedef __attribute__((ext_vector_type(8))) short bfrag;   // 8 bf16
typedef __attribute__((ext_vector_type(4))) float ffrag;   // 4 fp32 acc

__device__ __forceinline__ float bf_lo(unsigned int u) {
    return __uint_as_float(u << 16);
}
__device__ __forceinline__ float bf_hi(unsigned int u) {
    return __uint_as_float(u & 0xffff0000u);
}
__device__ __forceinline__ ushort_t f2bf(float f) {
    unsigned int x = __float_as_uint(f);
    unsigned int r = x + 0x7fffu + ((x >> 16) & 1u);
    return (ushort_t)(r >> 16);
}

// ---------------------------------------------------------------------------
// cast_feat: feat fp32 -> (a) abig[:, :128] bf16 (A-matrix for out GEMM),
//            (b) srcpack interleaved feat half: feature f at (f>>2)*8+4+(f&3).
// ---------------------------------------------------------------------------
__global__ __launch_bounds__(256) void cast_feat_kernel(
    const float* __restrict__ feat, ushort_t* __restrict__ abig,
    ushort_t* __restrict__ srcpack, int n)
{
    int i = blockIdx.x * 256 + threadIdx.x;
    if (i >= n * 16) return;
    int row = i >> 4, c = (i & 15) * 8;
    float4 a = *(const float4*)(feat + (size_t)row * F + c);
    float4 b = *(const float4*)(feat + (size_t)row * F + c + 4);
    ushort4 u0 = make_ushort4(f2bf(a.x), f2bf(a.y), f2bf(a.z), f2bf(a.w));
    ushort4 u1 = make_ushort4(f2bf(b.x), f2bf(b.y), f2bf(b.z), f2bf(b.w));
    *(ushort4*)(abig + (size_t)row * 256 + c) = u0;
    *(ushort4*)(abig + (size_t)row * 256 + c + 4) = u1;
    *(ushort4*)(srcpack + (size_t)row * 256 + c * 2 + 4) = u0;
    *(ushort4*)(srcpack + (size_t)row * 256 + c * 2 + 12) = u1;
}

// ---------------------------------------------------------------------------
// cast_w: build column-major bf16 B matrices.
//   btp[j*128+k] = w1-derived B[k][j] for C=feat@[w1[:F]|w1[F:]] (j=0..255)
//   btf[j*256+k] = wf[k][j]                                      (j=0..127)
// ---------------------------------------------------------------------------
__global__ __launch_bounds__(256) void cast_w_kernel(
    const float* __restrict__ w1, const float* __restrict__ wf,
    ushort_t* __restrict__ btp, ushort_t* __restrict__ btf)
{
    int i = blockIdx.x * 256 + threadIdx.x;   // 0..65535
    if (i < 32768) {
        int j = i >> 7, k = i & 127;
        float v = (j < 128) ? w1[(size_t)k * F + j]
                            : w1[(size_t)(128 + k) * F + (j - 128)];
        btp[i] = f2bf(v);
    } else {
        int idx = i - 32768;
        int j = idx >> 8, k = idx & 255;
        btf[idx] = f2bf(wf[(size_t)k * F + j]);
    }
}

// ---------------------------------------------------------------------------
// rowptr: row_ptr[v] = first edge index with dst >= v (dst sorted)
// ---------------------------------------------------------------------------
__global__ void rowptr_kernel(const int* __restrict__ dst,
                              int* __restrict__ row_ptr, int e, int n)
{
    int i = blockIdx.x * blockDim.x + threadIdx.x;
    if (i >= e) return;
    int d = dst[i];
    int prev = (i == 0) ? -1 : dst[i - 1];
    for (int v = prev + 1; v <= d; ++v) row_ptr[v] = i;
    if (i == e - 1) {
        for (int v = d + 1; v <= n; ++v) row_ptr[v] = e;
    }
}

// ---------------------------------------------------------------------------
// proj (MFMA): C[40000x256] = feat_bf @ B, then epilogue exp(2*(c+bias)).
// cols 0..127 -> e_dst (stride 128, +b1); cols 128..255 -> srcpack e_src half
// (interleaved). Block = 64 rows x 256 cols, 4 waves (wave w: cols 64w..).
// 16x16x32 bf16 MFMA; A: m=lane&15,k=quad*8+j; B col-major same; C/D:
// row=quad*4+reg, col=lane&15  [verified mappings].
// ---------------------------------------------------------------------------
#define PSTRIDE 136
__global__ __launch_bounds__(256) void proj_mfma_kernel(
    const ushort_t* __restrict__ abig, const ushort_t* __restrict__ btp,
    const float* __restrict__ b1, ushort_t* __restrict__ e_dst,
    ushort_t* __restrict__ srcpack, int n)
{
    __shared__ ushort_t As[64 * PSTRIDE];
    const int t = threadIdx.x;
    const int wv = t >> 6, lane = t & 63;
    const int lm = lane & 15, quad = lane >> 4;
    const int row0 = blockIdx.x * 64;
    const int col0 = wv * 64;

    for (int i = t; i < 1024; i += 256) {      // 64 rows x 128 k bf16
        int r = i >> 4, c8 = (i & 15) * 8;
        uint4 d = make_uint4(0, 0, 0, 0);
        if (row0 + r < n)
            d = *(const uint4*)(abig + (size_t)(row0 + r) * 256 + c8);
        *(uint4*)(As + r * PSTRIDE + c8) = d;
    }
    __syncthreads();

    ffrag acc[4][4];
#pragma unroll
    for (int mi = 0; mi < 4; ++mi)
#pragma unroll
        for (int ni = 0; ni < 4; ++ni) acc[mi][ni] = (ffrag){0.f, 0.f, 0.f, 0.f};

#pragma unroll
    for (int ks = 0; ks < 4; ++ks) {
        bfrag bfr[4];
#pragma unroll
        for (int ni = 0; ni < 4; ++ni)
            bfr[ni] = *(const bfrag*)(btp + (size_t)(col0 + ni * 16 + lm) * 128
                                      + ks * 32 + quad * 8);
#pragma unroll
        for (int mi = 0; mi < 4; ++mi) {
            bfrag af = *(const bfrag*)(As + (mi * 16 + lm) * PSTRIDE
                                       + ks * 32 + quad * 8);
#pragma unroll
            for (int ni = 0; ni < 4; ++ni)
                acc[mi][ni] = __builtin_amdgcn_mfma_f32_16x16x32_bf16(
                    af, bfr[ni], acc[mi][ni], 0, 0, 0);
        }
    }

#pragma unroll
    for (int ni = 0; ni < 4; ++ni) {
        const int j = col0 + ni * 16 + lm;
        const float bias = (j < F) ? b1[j] : 0.f;
#pragma unroll
        for (int mi = 0; mi < 4; ++mi) {
#pragma unroll
            for (int r = 0; r < 4; ++r) {
                int row = row0 + mi * 16 + quad * 4 + r;
                if (row >= n) continue;
                ushort_t ub = f2bf(__expf(2.f * (acc[mi][ni][r] + bias)));
                if (j < F) {
                    e_dst[(size_t)row * F + j] = ub;
                } else {
                    int f = j - F;
                    srcpack[(size_t)row * 256 + (f >> 2) * 8 + (f & 3)] = ub;
                }
            }
        }
    }
}

// ---------------------------------------------------------------------------
// fused score+softmax+aggregate v3: one 32-lane half-wave per node.
// All lanes: 4 score feats (e_src) + 4 agg feats (feat) from one uint4 gather.
// Static softmax max M = b2 + sum|w2| (tanh<1 => score<M): no online rescale,
// edges fully independent -> 2-edge ILP. wgt = exp(K - 2*pv), K = sum(w2)-sum|w2|.
// Writes neigh bf16 into abig[:, 128:].
// ---------------------------------------------------------------------------
__global__ __launch_bounds__(256) void fused_kernel(
    const ushort_t* __restrict__ e_dst, const ushort_t* __restrict__ srcpack,
    const int* __restrict__ src, const int* __restrict__ row_ptr,
    const float* __restrict__ w2, ushort_t* __restrict__ abig, int n)
{
    const int v = (int)((blockIdx.x * 256u + threadIdx.x) >> 5);
    const int fl = threadIdx.x & 31;
    const int sbase = threadIdx.x & 32;

    const float4 wv4 = ((const float4*)w2)[fl];
    const float w0 = wv4.x, w1_ = wv4.y, w2_ = wv4.z, w3_ = wv4.w;
    float sw = w0 + w1_ + w2_ + w3_;
    float aw = fabsf(w0) + fabsf(w1_) + fabsf(w2_) + fabsf(w3_);
#pragma unroll
    for (int off = 16; off; off >>= 1) {
        sw += __shfl_xor(sw, off, 64);
        aw += __shfl_xor(aw, off, 64);
    }
    const float K = sw - aw;           // score - M = K - 2*pv  (always <= 0)

    if (v >= n) return;
    const int begin = row_ptr[v], end = row_ptr[v + 1];

    const uint2 ud = *(const uint2*)(e_dst + (size_t)v * F + fl * 4);
    const float ea0 = bf_lo(ud.x), ea1 = bf_hi(ud.x);
    const float ea2 = bf_lo(ud.y), ea3 = bf_hi(ud.y);

    float s = 0.f, a0 = 0.f, a1 = 0.f, a2 = 0.f, a3 = 0.f;

    for (int cb = begin; cb < end; cb += 32) {
        const int clen = min(32, end - cb);
        const int sv = (fl < clen) ? src[cb + fl] : 0;
        int jj = 0;
        for (; jj + 2 <= clen; jj += 2) {
            const int s0 = __shfl(sv, sbase + jj, 64);
            const int s1 = __shfl(sv, sbase + jj + 1, 64);
            const uint4 u0 = ((const uint4*)(srcpack + (size_t)s0 * 256))[fl];
            const uint4 u1 = ((const uint4*)(srcpack + (size_t)s1 * 256))[fl];
            float r, p0, p1;
            r = __builtin_amdgcn_rcpf(fmaf(ea0, bf_lo(u0.x), 1.f)); p0 = w0 * r;
            r = __builtin_amdgcn_rcpf(fmaf(ea1, bf_hi(u0.x), 1.f)); p0 = fmaf(w1_, r, p0);
            r = __builtin_amdgcn_rcpf(fmaf(ea2, bf_lo(u0.y), 1.f)); p0 = fmaf(w2_, r, p0);
            r = __builtin_amdgcn_rcpf(fmaf(ea3, bf_hi(u0.y), 1.f)); p0 = fmaf(w3_, r, p0);
            r = __builtin_amdgcn_rcpf(fmaf(ea0, bf_lo(u1.x), 1.f)); p1 = w0 * r;
            r = __builtin_amdgcn_rcpf(fmaf(ea1, bf_hi(u1.x), 1.f)); p1 = fmaf(w1_, r, p1);
            r = __builtin_amdgcn_rcpf(fmaf(ea2, bf_lo(u1.y), 1.f)); p1 = fmaf(w2_, r, p1);
            r = __builtin_amdgcn_rcpf(fmaf(ea3, bf_hi(u1.y), 1.f)); p1 = fmaf(w3_, r, p1);
#pragma unroll
            for (int off = 16; off; off >>= 1) {
                p0 += __shfl_xor(p0, off, 64);
                p1 += __shfl_xor(p1, off, 64);
            }
            const float g0 = __expf(fmaf(-2.f, p0, K));
            const float g1 = __expf(fmaf(-2.f, p1, K));
            s += g0 + g1;
            a0 = fmaf(g0, bf_lo(u0.z), fmaf(g1, bf_lo(u1.z), a0));
            a1 = fmaf(g0, bf_hi(u0.z), fmaf(g1, bf_hi(u1.z), a1));
            a2 = fmaf(g0, bf_lo(u0.w), fmaf(g1, bf_lo(u1.w), a2));
            a3 = fmaf(g0, bf_hi(u0.w), fmaf(g1, bf_hi(u1.w), a3));
        }
        if (jj < clen) {
            const int s0 = __shfl(sv, sbase + jj, 64);
            const uint4 u0 = ((const uint4*)(srcpack + (size_t)s0 * 256))[fl];
            float r, p0;
            r = __builtin_amdgcn_rcpf(fmaf(ea0, bf_lo(u0.x), 1.f)); p0 = w0 * r;
            r = __builtin_amdgcn_rcpf(fmaf(ea1, bf_hi(u0.x), 1.f)); p0 = fmaf(w1_, r, p0);
            r = __builtin_amdgcn_rcpf(fmaf(ea2, bf_lo(u0.y), 1.f)); p0 = fmaf(w2_, r, p0);
            r = __builtin_amdgcn_rcpf(fmaf(ea3, bf_hi(u0.y), 1.f)); p0 = fmaf(w3_, r, p0);
#pragma unroll
            for (int off = 16; off; off >>= 1) p0 += __shfl_xor(p0, off, 64);
            const float g0 = __expf(fmaf(-2.f, p0, K));
            s += g0;
            a0 = fmaf(g0, bf_lo(u0.z), a0);
            a1 = fmaf(g0, bf_hi(u0.z), a1);
            a2 = fmaf(g0, bf_lo(u0.w), a2);
            a3 = fmaf(g0, bf_hi(u0.w), a3);
        }
    }

    const float inv = (end > begin) ? 1.f / s : 0.f;
    ushort4 o = make_ushort4(f2bf(a0 * inv), f2bf(a1 * inv),
                             f2bf(a2 * inv), f2bf(a3 * inv));
    *(ushort4*)(abig + (size_t)v * 256 + 128 + fl * 4) = o;
}

// ---------------------------------------------------------------------------
// out (MFMA): out[40000x128] = abig(bf16, K=256) @ btf + bf.
// Block = 64 rows x 128 cols, 4 waves (wave w: cols 32w..32w+31).
// ---------------------------------------------------------------------------
#define OSTRIDE 264
__global__ __launch_bounds__(256) void out_mfma_kernel(
    const ushort_t* __restrict__ abig, const ushort_t* __restrict__ btf,
    const float* __restrict__ bfv, float* __restrict__ out, int n)
{
    __shared__ ushort_t As[64 * OSTRIDE];
    const int t = threadIdx.x;
    const int wv = t >> 6, lane = t & 63;
    const int lm = lane & 15, quad = lane >> 4;
    const int row0 = blockIdx.x * 64;
    const int col0 = wv * 32;

    for (int i = t; i < 2048; i += 256) {      // 64 rows x 256 k bf16
        int r = i >> 5, c8 = (i & 31) * 8;
        uint4 d = make_uint4(0, 0, 0, 0);
        if (row0 + r < n)
            d = *(const uint4*)(abig + (size_t)(row0 + r) * 256 + c8);
        *(uint4*)(As + r * OSTRIDE + c8) = d;
    }
    __syncthreads();

    ffrag acc[4][2];
#pragma unroll
    for (int mi = 0; mi < 4; ++mi)
#pragma unroll
        for (int ni = 0; ni < 2; ++ni) acc[mi][ni] = (ffrag){0.f, 0.f, 0.f, 0.f};

#pragma unroll
    for (int ks = 0; ks < 8; ++ks) {
        bfrag bfr[2];
#pragma unroll
        for (int ni = 0; ni < 2; ++ni)
            bfr[ni] = *(const bfrag*)(btf + (size_t)(col0 + ni * 16 + lm) * 256
                                      + ks * 32 + quad * 8);
#pragma unroll
        for (int mi = 0; mi < 4; ++mi) {
            bfrag af = *(const bfrag*)(As + (mi * 16 + lm) * OSTRIDE
                                       + ks * 32 + quad * 8);
#pragma unroll
            for (int ni = 0; ni < 2; ++ni)
                acc[mi][ni] = __builtin_amdgcn_mfma_f32_16x16x32_bf16(
                    af, bfr[ni], acc[mi][ni], 0, 0, 0);
        }
    }

#pragma unroll
    for (int ni = 0; ni < 2; ++ni) {
        const int j = col0 + ni * 16 + lm;
        const float bb = bfv[j];
#pragma unroll
        for (int mi = 0; mi < 4; ++mi) {
#pragma unroll
            for (int r = 0; r < 4; ++r) {
                int row = row0 + mi * 16 + quad * 4 + r;
                if (row < n) out[(size_t)row * OUT + j] = acc[mi][ni][r] + bb;
            }
        }
    }
}

// ---------------------------------------------------------------------------
extern "C" void kernel_launch(void* const* d_in, const int* in_sizes, int n_in,
                              void* d_out, int out_size, void* d_ws, size_t ws_size,
                              hipStream_t stream)
{
    const float* feat = (const float*)d_in[0];
    const int*   src  = (const int*)d_in[1];
    const int*   dst  = (const int*)d_in[2];
    const float* w1   = (const float*)d_in[3];
    const float* b1   = (const float*)d_in[4];
    const float* w2   = (const float*)d_in[5];
    const float* b2   = (const float*)d_in[6];  (void)b2; // cancels in softmax
    const float* wf   = (const float*)d_in[7];
    const float* bfv  = (const float*)d_in[8];
    float* out = (float*)d_out;

    const int n = in_sizes[0] / F;   // 40000
    const int e = in_sizes[1];       // 640000

    ushort_t* abig    = (ushort_t*)d_ws;                 // n*256 bf16 [feat|neigh]
    ushort_t* e_dst   = abig + (size_t)n * 256;          // n*128 bf16
    ushort_t* srcpack = e_dst + (size_t)n * 128;         // n*256 bf16 interleaved
    ushort_t* btp     = srcpack + (size_t)n * 256;       // 256*128 bf16
    ushort_t* btf     = btp + 32768;                     // 128*256 bf16
    int* row_ptr      = (int*)(btf + 32768);             // n+1

    cast_feat_kernel<<<(n * 16 + 255) / 256, 256, 0, stream>>>(feat, abig, srcpack, n);
    cast_w_kernel<<<256, 256, 0, stream>>>(w1, wf, btp, btf);
    rowptr_kernel<<<(e + 255) / 256, 256, 0, stream>>>(dst, row_ptr, e, n);
    proj_mfma_kernel<<<(n + 63) / 64, 256, 0, stream>>>(abig, btp, b1, e_dst, srcpack, n);
    fused_kernel<<<(n + 7) / 8, 256, 0, stream>>>(e_dst, srcpack, src, row_ptr, w2, abig, n);
    out_mfma_kernel<<<(n + 63) / 64, 256, 0, stream>>>(abig, btf, bfv, out, n);
}

// Round 8
// 177.731 us; speedup vs baseline: 2.6031x; 1.0064x over previous
//
#include <hip/hip_runtime.h>
#include <math.h>

#define F 128
#define OUT 128

typedef unsigned short ushort_t;
typedef __attribute__((ext_vector_type(8))) short bfrag;   // 8 bf16
typedef __attribute__((ext_vector_type(4))) float ffrag;   // 4 fp32 acc

union BU { unsigned u[4]; bfrag b; };

__device__ __forceinline__ float bf_lo(unsigned int u) {
    return __uint_as_float(u << 16);
}
__device__ __forceinline__ float bf_hi(unsigned int u) {
    return __uint_as_float(u & 0xffff0000u);
}
__device__ __forceinline__ ushort_t f2bf(float f) {
    unsigned int x = __float_as_uint(f);
    unsigned int r = x + 0x7fffu + ((x >> 16) & 1u);
    return (ushort_t)(r >> 16);
}
__device__ __forceinline__ unsigned pk2(float lo, float hi) {
    return (unsigned)f2bf(lo) | ((unsigned)f2bf(hi) << 16);
}

// ---------------------------------------------------------------------------
// K1 (mega): blocks [0,nproj) = proj MFMA; blocks [nproj, nproj+nrp) = rowptr.
//
// proj: C[64x256] = feat_bf @ B  (B col j<128: w1[k][j]; j>=128: w1[128+k][j-128])
//   epilogue exp(2*(c+bias)) -> e_dst (j<128, +b1) / srcpack e_src half (interleaved).
//   Staging also emits abig[:, :128] (bf16 feat) and srcpack feat half.
//   B-frags converted from fp32 w1 on the fly (w1 is L2-hot, 16-lane coalesced).
// ---------------------------------------------------------------------------
#define PSTRIDE 136
__global__ __launch_bounds__(256) void mega_kernel(
    const float* __restrict__ feat, const float* __restrict__ w1,
    const float* __restrict__ b1, const int* __restrict__ dst,
    int* __restrict__ row_ptr, ushort_t* __restrict__ e_dst,
    ushort_t* __restrict__ srcpack, ushort_t* __restrict__ abig,
    int n, int e, int nproj)
{
    if ((int)blockIdx.x >= nproj) {
        // ---- rowptr part ----
        int i = ((int)blockIdx.x - nproj) * 256 + threadIdx.x;
        if (i >= e) return;
        int d = dst[i];
        int prev = (i == 0) ? -1 : dst[i - 1];
        for (int v = prev + 1; v <= d; ++v) row_ptr[v] = i;
        if (i == e - 1) {
            for (int v = d + 1; v <= n; ++v) row_ptr[v] = e;
        }
        return;
    }

    // ---- proj part ----
    __shared__ ushort_t As[64 * PSTRIDE];
    const int t = threadIdx.x;
    const int wv = t >> 6, lane = t & 63;
    const int lm = lane & 15, quad = lane >> 4;
    const int row0 = blockIdx.x * 64;
    const int col0 = wv * 64;

    // staging: thread t handles row r = t>>2, feats 32q..32q+31 (q = t&3).
    {
        const int r = t >> 2, q = t & 3;
        const int row = row0 + r;
        unsigned up[16];
        if (row < n) {
            const float* fp = feat + (size_t)row * F + 32 * q;
#pragma unroll
            for (int i4 = 0; i4 < 8; ++i4) {
                float4 a = *(const float4*)(fp + 4 * i4);
                up[2 * i4]     = pk2(a.x, a.y);
                up[2 * i4 + 1] = pk2(a.z, a.w);
            }
        } else {
#pragma unroll
            for (int i2 = 0; i2 < 16; ++i2) up[i2] = 0;
        }
        // LDS A tile
#pragma unroll
        for (int i4 = 0; i4 < 4; ++i4)
            *(uint4*)(As + r * PSTRIDE + 32 * q + 8 * i4) =
                make_uint4(up[4 * i4], up[4 * i4 + 1], up[4 * i4 + 2], up[4 * i4 + 3]);
        if (row < n) {
            // abig[:, :128] feat bf16 (contiguous)
#pragma unroll
            for (int i4 = 0; i4 < 4; ++i4)
                *(uint4*)(abig + (size_t)row * 256 + 32 * q + 8 * i4) =
                    make_uint4(up[4 * i4], up[4 * i4 + 1], up[4 * i4 + 2], up[4 * i4 + 3]);
            // srcpack feat half: feature f -> (f>>2)*8 + 4 + (f&3)
#pragma unroll
            for (int i4 = 0; i4 < 8; ++i4)
                *(uint2*)(srcpack + (size_t)row * 256 + (8 * q + i4) * 8 + 4) =
                    make_uint2(up[2 * i4], up[2 * i4 + 1]);
        }
    }
    __syncthreads();

    ffrag acc[4][4];
#pragma unroll
    for (int mi = 0; mi < 4; ++mi)
#pragma unroll
        for (int ni = 0; ni < 4; ++ni) acc[mi][ni] = (ffrag){0.f, 0.f, 0.f, 0.f};

#pragma unroll
    for (int ks = 0; ks < 4; ++ks) {
        bfrag bfr[4];
#pragma unroll
        for (int ni = 0; ni < 4; ++ni) {
            const int jj = col0 + ni * 16 + lm;
            const float* wcol = (jj < F) ? (w1 + jj) : (w1 + (size_t)F * F + (jj - F));
            const int k0 = ks * 32 + quad * 8;
            BU bu;
#pragma unroll
            for (int l = 0; l < 4; ++l) {
                float x0 = wcol[(size_t)(k0 + 2 * l) * F];
                float x1 = wcol[(size_t)(k0 + 2 * l + 1) * F];
                bu.u[l] = pk2(x0, x1);
            }
            bfr[ni] = bu.b;
        }
#pragma unroll
        for (int mi = 0; mi < 4; ++mi) {
            bfrag af = *(const bfrag*)(As + (mi * 16 + lm) * PSTRIDE
                                       + ks * 32 + quad * 8);
#pragma unroll
            for (int ni = 0; ni < 4; ++ni)
                acc[mi][ni] = __builtin_amdgcn_mfma_f32_16x16x32_bf16(
                    af, bfr[ni], acc[mi][ni], 0, 0, 0);
        }
    }

#pragma unroll
    for (int ni = 0; ni < 4; ++ni) {
        const int j = col0 + ni * 16 + lm;
        const float bias = (j < F) ? b1[j] : 0.f;
#pragma unroll
        for (int mi = 0; mi < 4; ++mi) {
#pragma unroll
            for (int r = 0; r < 4; ++r) {
                int row = row0 + mi * 16 + quad * 4 + r;
                if (row >= n) continue;
                ushort_t ub = f2bf(__expf(2.f * (acc[mi][ni][r] + bias)));
                if (j < F) {
                    e_dst[(size_t)row * F + j] = ub;
                } else {
                    int f = j - F;
                    srcpack[(size_t)row * 256 + (f >> 2) * 8 + (f & 3)] = ub;
                }
            }
        }
    }
}

// ---------------------------------------------------------------------------
// K2: fused score+softmax+aggregate. One 32-lane half-wave per node; per edge
// one uint4 gather gives 4 e_src + 4 feat bf16 per lane. Static softmax bound
// M = b2 + sum|w2| (tanh<1 => score<M): edges independent -> 4-edge ILP.
// wgt = exp(K - 2*pv), K = sum(w2) - sum|w2|. Writes neigh bf16 to abig[:,128:].
// ---------------------------------------------------------------------------
__global__ __launch_bounds__(256) void fused_kernel(
    const ushort_t* __restrict__ e_dst, const ushort_t* __restrict__ srcpack,
    const int* __restrict__ src, const int* __restrict__ row_ptr,
    const float* __restrict__ w2, ushort_t* __restrict__ abig, int n)
{
    const int v = (int)((blockIdx.x * 256u + threadIdx.x) >> 5);
    const int fl = threadIdx.x & 31;
    const int sbase = threadIdx.x & 32;

    const float4 wv4 = ((const float4*)w2)[fl];
    const float w0 = wv4.x, w1_ = wv4.y, w2_ = wv4.z, w3_ = wv4.w;
    float sw = w0 + w1_ + w2_ + w3_;
    float aw = fabsf(w0) + fabsf(w1_) + fabsf(w2_) + fabsf(w3_);
#pragma unroll
    for (int off = 16; off; off >>= 1) {
        sw += __shfl_xor(sw, off, 64);
        aw += __shfl_xor(aw, off, 64);
    }
    const float K = sw - aw;           // score - M = K - 2*pv  (always <= 0)

    if (v >= n) return;
    const int begin = row_ptr[v], end = row_ptr[v + 1];

    const uint2 ud = *(const uint2*)(e_dst + (size_t)v * F + fl * 4);
    const float ea0 = bf_lo(ud.x), ea1 = bf_hi(ud.x);
    const float ea2 = bf_lo(ud.y), ea3 = bf_hi(ud.y);

    float s = 0.f, a0 = 0.f, a1 = 0.f, a2 = 0.f, a3 = 0.f;

    for (int cb = begin; cb < end; cb += 32) {
        const int clen = min(32, end - cb);
        const int sv = (fl < clen) ? src[cb + fl] : 0;
        int jj = 0;
        for (; jj + 4 <= clen; jj += 4) {
            uint4 u[4];
#pragma unroll
            for (int q = 0; q < 4; ++q) {
                const int sq = __shfl(sv, sbase + jj + q, 64);
                u[q] = ((const uint4*)(srcpack + (size_t)sq * 256))[fl];
            }
            float p[4];
#pragma unroll
            for (int q = 0; q < 4; ++q) {
                float r;
                r = __builtin_amdgcn_rcpf(fmaf(ea0, bf_lo(u[q].x), 1.f)); p[q] = w0 * r;
                r = __builtin_amdgcn_rcpf(fmaf(ea1, bf_hi(u[q].x), 1.f)); p[q] = fmaf(w1_, r, p[q]);
                r = __builtin_amdgcn_rcpf(fmaf(ea2, bf_lo(u[q].y), 1.f)); p[q] = fmaf(w2_, r, p[q]);
                r = __builtin_amdgcn_rcpf(fmaf(ea3, bf_hi(u[q].y), 1.f)); p[q] = fmaf(w3_, r, p[q]);
            }
#pragma unroll
            for (int off = 16; off; off >>= 1) {
#pragma unroll
                for (int q = 0; q < 4; ++q) p[q] += __shfl_xor(p[q], off, 64);
            }
            float g[4];
#pragma unroll
            for (int q = 0; q < 4; ++q) g[q] = __expf(fmaf(-2.f, p[q], K));
            s += (g[0] + g[1]) + (g[2] + g[3]);
#pragma unroll
            for (int q = 0; q < 4; ++q) {
                a0 = fmaf(g[q], bf_lo(u[q].z), a0);
                a1 = fmaf(g[q], bf_hi(u[q].z), a1);
                a2 = fmaf(g[q], bf_lo(u[q].w), a2);
                a3 = fmaf(g[q], bf_hi(u[q].w), a3);
            }
        }
        for (; jj < clen; ++jj) {
            const int s0 = __shfl(sv, sbase + jj, 64);
            const uint4 u0 = ((const uint4*)(srcpack + (size_t)s0 * 256))[fl];
            float r, p0;
            r = __builtin_amdgcn_rcpf(fmaf(ea0, bf_lo(u0.x), 1.f)); p0 = w0 * r;
            r = __builtin_amdgcn_rcpf(fmaf(ea1, bf_hi(u0.x), 1.f)); p0 = fmaf(w1_, r, p0);
            r = __builtin_amdgcn_rcpf(fmaf(ea2, bf_lo(u0.y), 1.f)); p0 = fmaf(w2_, r, p0);
            r = __builtin_amdgcn_rcpf(fmaf(ea3, bf_hi(u0.y), 1.f)); p0 = fmaf(w3_, r, p0);
#pragma unroll
            for (int off = 16; off; off >>= 1) p0 += __shfl_xor(p0, off, 64);
            const float g0 = __expf(fmaf(-2.f, p0, K));
            s += g0;
            a0 = fmaf(g0, bf_lo(u0.z), a0);
            a1 = fmaf(g0, bf_hi(u0.z), a1);
            a2 = fmaf(g0, bf_lo(u0.w), a2);
            a3 = fmaf(g0, bf_hi(u0.w), a3);
        }
    }

    const float inv = (end > begin) ? 1.f / s : 0.f;
    ushort4 o = make_ushort4(f2bf(a0 * inv), f2bf(a1 * inv),
                             f2bf(a2 * inv), f2bf(a3 * inv));
    *(ushort4*)(abig + (size_t)v * 256 + 128 + fl * 4) = o;
}

// ---------------------------------------------------------------------------
// K3: out[40000x128] = abig(bf16, K=256) @ wf + bf.  B-frags converted from
// fp32 wf on the fly (wf L2-hot, 16-lane coalesced loads).
// Block = 64 rows x 128 cols, 4 waves (wave w: cols 32w..32w+31).
// ---------------------------------------------------------------------------
#define OSTRIDE 264
__global__ __launch_bounds__(256) void out_mfma_kernel(
    const ushort_t* __restrict__ abig, const float* __restrict__ wf,
    const float* __restrict__ bfv, float* __restrict__ out, int n)
{
    __shared__ ushort_t As[64 * OSTRIDE];
    const int t = threadIdx.x;
    const int wv = t >> 6, lane = t & 63;
    const int lm = lane & 15, quad = lane >> 4;
    const int row0 = blockIdx.x * 64;
    const int col0 = wv * 32;

    for (int i = t; i < 2048; i += 256) {      // 64 rows x 256 k bf16
        int r = i >> 5, c8 = (i & 31) * 8;
        uint4 d = make_uint4(0, 0, 0, 0);
        if (row0 + r < n)
            d = *(const uint4*)(abig + (size_t)(row0 + r) * 256 + c8);
        *(uint4*)(As + r * OSTRIDE + c8) = d;
    }
    __syncthreads();

    ffrag acc[4][2];
#pragma unroll
    for (int mi = 0; mi < 4; ++mi)
#pragma unroll
        for (int ni = 0; ni < 2; ++ni) acc[mi][ni] = (ffrag){0.f, 0.f, 0.f, 0.f};

#pragma unroll
    for (int ks = 0; ks < 8; ++ks) {
        bfrag bfr[2];
#pragma unroll
        for (int ni = 0; ni < 2; ++ni) {
            const int jj = col0 + ni * 16 + lm;
            const int k0 = ks * 32 + quad * 8;
            BU bu;
#pragma unroll
            for (int l = 0; l < 4; ++l) {
                float x0 = wf[(size_t)(k0 + 2 * l) * F + jj];
                float x1 = wf[(size_t)(k0 + 2 * l + 1) * F + jj];
                bu.u[l] = pk2(x0, x1);
            }
            bfr[ni] = bu.b;
        }
#pragma unroll
        for (int mi = 0; mi < 4; ++mi) {
            bfrag af = *(const bfrag*)(As + (mi * 16 + lm) * OSTRIDE
                                       + ks * 32 + quad * 8);
#pragma unroll
            for (int ni = 0; ni < 2; ++ni)
                acc[mi][ni] = __builtin_amdgcn_mfma_f32_16x16x32_bf16(
                    af, bfr[ni], acc[mi][ni], 0, 0, 0);
        }
    }

#pragma unroll
    for (int ni = 0; ni < 2; ++ni) {
        const int j = col0 + ni * 16 + lm;
        const float bb = bfv[j];
#pragma unroll
        for (int mi = 0; mi < 4; ++mi) {
#pragma unroll
            for (int r = 0; r < 4; ++r) {
                int row = row0 + mi * 16 + quad * 4 + r;
                if (row < n) out[(size_t)row * OUT + j] = acc[mi][ni][r] + bb;
            }
        }
    }
}

// ---------------------------------------------------------------------------
extern "C" void kernel_launch(void* const* d_in, const int* in_sizes, int n_in,
                              void* d_out, int out_size, void* d_ws, size_t ws_size,
                              hipStream_t stream)
{
    const float* feat = (const float*)d_in[0];
    const int*   src  = (const int*)d_in[1];
    const int*   dst  = (const int*)d_in[2];
    const float* w1   = (const float*)d_in[3];
    const float* b1   = (const float*)d_in[4];
    const float* w2   = (const float*)d_in[5];
    const float* b2   = (const float*)d_in[6];  (void)b2; // cancels in softmax
    const float* wf   = (const float*)d_in[7];
    const float* bfv  = (const float*)d_in[8];
    float* out = (float*)d_out;

    const int n = in_sizes[0] / F;   // 40000
    const int e = in_sizes[1];       // 640000

    ushort_t* abig    = (ushort_t*)d_ws;                 // n*256 bf16 [feat|neigh]
    ushort_t* e_dst   = abig + (size_t)n * 256;          // n*128 bf16
    ushort_t* srcpack = e_dst + (size_t)n * 128;         // n*256 bf16 interleaved
    int* row_ptr      = (int*)(srcpack + (size_t)n * 256); // n+1

    const int nproj = (n + 63) / 64;        // 625
    const int nrp   = (e + 255) / 256;      // 2500

    mega_kernel<<<nproj + nrp, 256, 0, stream>>>(
        feat, w1, b1, dst, row_ptr, e_dst, srcpack, abig, n, e, nproj);
    fused_kernel<<<(n + 7) / 8, 256, 0, stream>>>(
        e_dst, srcpack, src, row_ptr, w2, abig, n);
    out_mfma_kernel<<<(n + 63) / 64, 256, 0, stream>>>(abig, wf, bfv, out, n);
}

// Round 9
// 170.139 us; speedup vs baseline: 2.7192x; 1.0446x over previous
//
#include <hip/hip_runtime.h>
#include <math.h>

#define F 128
#define OUT 128

typedef unsigned short ushort_t;
typedef __attribute__((ext_vector_type(8))) short bfrag;   // 8 bf16
typedef __attribute__((ext_vector_type(4))) float ffrag;   // 4 fp32 acc

__device__ __forceinline__ float bf_lo(unsigned int u) {
    return __uint_as_float(u << 16);
}
__device__ __forceinline__ float bf_hi(unsigned int u) {
    return __uint_as_float(u & 0xffff0000u);
}
__device__ __forceinline__ ushort_t f2bf(float f) {
    unsigned int x = __float_as_uint(f);
    unsigned int r = x + 0x7fffu + ((x >> 16) & 1u);
    return (ushort_t)(r >> 16);
}
__device__ __forceinline__ unsigned pk2(float lo, float hi) {
    return (unsigned)f2bf(lo) | ((unsigned)f2bf(hi) << 16);
}

// ---------------------------------------------------------------------------
// prep: heterogeneous grid.
//  part0: feat fp32 -> abig[:, :128] bf16 + srcpack feat-half (interleaved:
//         feature f at (f>>2)*8 + 4 + (f&3)).  All vector stores.
//  part1: btp[j*128+k] = bf16(B[k][j]), B = [w1[:F] | w1[F:]] cols j=0..255.
//  part2: btf[j*256+k] = bf16(wf[k][j]), j=0..127.
//  part3: rowptr (dst sorted).
// ---------------------------------------------------------------------------
__global__ __launch_bounds__(256) void prep_kernel(
    const float* __restrict__ feat, const float* __restrict__ w1,
    const float* __restrict__ wf, const int* __restrict__ dst,
    ushort_t* __restrict__ abig, ushort_t* __restrict__ srcpack,
    ushort_t* __restrict__ btp, ushort_t* __restrict__ btf,
    int* __restrict__ row_ptr, int n, int e, int nb0, int nb1, int nb2)
{
    const int b = blockIdx.x, t = threadIdx.x;
    if (b < nb0) {
        int i = b * 256 + t;
        if (i >= n * 16) return;
        int row = i >> 4, c = (i & 15) * 8;
        float4 a = *(const float4*)(feat + (size_t)row * F + c);
        float4 bb = *(const float4*)(feat + (size_t)row * F + c + 4);
        unsigned p0 = pk2(a.x, a.y), p1 = pk2(a.z, a.w);
        unsigned p2 = pk2(bb.x, bb.y), p3 = pk2(bb.z, bb.w);
        *(uint4*)(abig + (size_t)row * 256 + c) = make_uint4(p0, p1, p2, p3);
        *(uint2*)(srcpack + (size_t)row * 256 + c * 2 + 4) = make_uint2(p0, p1);
        *(uint2*)(srcpack + (size_t)row * 256 + c * 2 + 12) = make_uint2(p2, p3);
    } else if (b < nb0 + nb1) {
        int idx = (b - nb0) * 256 + t;                 // 0..32767
        int j = idx >> 7, k = idx & 127;
        float v = (j < F) ? w1[(size_t)k * F + j]
                          : w1[(size_t)(F + k) * F + (j - F)];
        btp[idx] = f2bf(v);
    } else if (b < nb0 + nb1 + nb2) {
        int idx = (b - nb0 - nb1) * 256 + t;           // 0..32767
        int j = idx >> 8, k = idx & 255;
        btf[idx] = f2bf(wf[(size_t)k * F + j]);
    } else {
        int i = (b - nb0 - nb1 - nb2) * 256 + t;
        if (i >= e) return;
        int d = dst[i];
        int prev = (i == 0) ? -1 : dst[i - 1];
        for (int v = prev + 1; v <= d; ++v) row_ptr[v] = i;
        if (i == e - 1) {
            for (int v = d + 1; v <= n; ++v) row_ptr[v] = e;
        }
    }
}

// ---------------------------------------------------------------------------
// G1 (proj): C[n x 256] = abig_feat(bf16) @ btp, epilogue exp(2*(c+bias)).
// Block = 64 rows x 256 cols, 4 waves (wave w: cols 64w..64w+63).
// B-fragments hoisted to registers before K-loop (no global in MFMA loop).
// Epilogue: LDS transpose per wave -> coalesced uint4/uint2 stores.
// cols<128 -> e_dst (+b1); cols>=128 -> srcpack e_src half (interleaved).
// ---------------------------------------------------------------------------
#define PST 136
__global__ __launch_bounds__(256) void proj_gemm_kernel(
    const ushort_t* __restrict__ abig, const ushort_t* __restrict__ btp,
    const float* __restrict__ b1, ushort_t* __restrict__ e_dst,
    ushort_t* __restrict__ srcpack, int n)
{
    __shared__ ushort_t As[64 * PST];        // 17408 B
    __shared__ ushort_t Ep[4][16 * 80];      // 10240 B
    const int t = threadIdx.x;
    const int wv = t >> 6, lane = t & 63;
    const int lm = lane & 15, quad = lane >> 4;
    const int row0 = blockIdx.x * 64, col0 = wv * 64;

#pragma unroll
    for (int k = 0; k < 4; ++k) {            // 64 rows x 16 uint4, coalesced
        int l = k * 256 + t;
        int r = l >> 4, ch = l & 15;
        uint4 d = make_uint4(0, 0, 0, 0);
        if (row0 + r < n) d = *(const uint4*)(abig + (size_t)(row0 + r) * 256 + ch * 8);
        *(uint4*)(As + r * PST + ch * 8) = d;
    }
    __syncthreads();

    bfrag bfr[4][4];
#pragma unroll
    for (int ks = 0; ks < 4; ++ks)
#pragma unroll
        for (int ni = 0; ni < 4; ++ni)
            bfr[ks][ni] = *(const bfrag*)(btp + (size_t)(col0 + ni * 16 + lm) * 128
                                          + ks * 32 + quad * 8);

    ffrag acc[4][4];
#pragma unroll
    for (int mi = 0; mi < 4; ++mi)
#pragma unroll
        for (int ni = 0; ni < 4; ++ni) acc[mi][ni] = (ffrag){0.f, 0.f, 0.f, 0.f};

#pragma unroll
    for (int ks = 0; ks < 4; ++ks)
#pragma unroll
        for (int mi = 0; mi < 4; ++mi) {
            bfrag af = *(const bfrag*)(As + (mi * 16 + lm) * PST + ks * 32 + quad * 8);
#pragma unroll
            for (int ni = 0; ni < 4; ++ni)
                acc[mi][ni] = __builtin_amdgcn_mfma_f32_16x16x32_bf16(
                    af, bfr[ks][ni], acc[mi][ni], 0, 0, 0);
        }

    float bias[4];
#pragma unroll
    for (int ni = 0; ni < 4; ++ni)
        bias[ni] = (col0 < F) ? b1[col0 + ni * 16 + lm] : 0.f;

#pragma unroll
    for (int mi = 0; mi < 4; ++mi) {
        // compute-layout write into per-wave patch (conflict-free)
#pragma unroll
        for (int ni = 0; ni < 4; ++ni)
#pragma unroll
            for (int r = 0; r < 4; ++r)
                Ep[wv][(quad * 4 + r) * 80 + ni * 16 + lm] =
                    f2bf(__expf(2.f * (acc[mi][ni][r] + bias[ni])));
        // coalesced read-out: 2 passes x 8 rows x 8 lanes x 16B
#pragma unroll
        for (int ps = 0; ps < 2; ++ps) {
            int rl = ps * 8 + (lane >> 3), co = (lane & 7) * 8;
            uint4 vv = *(const uint4*)(&Ep[wv][rl * 80 + co]);
            int grow = row0 + mi * 16 + rl;
            if (grow < n) {
                if (col0 < F) {
                    *(uint4*)(e_dst + (size_t)grow * F + col0 + co) = vv;
                } else {
                    int f0 = col0 - F + co;   // multiple of 8
                    *(uint2*)(srcpack + (size_t)grow * 256 + f0 * 2) =
                        make_uint2(vv.x, vv.y);
                    *(uint2*)(srcpack + (size_t)grow * 256 + f0 * 2 + 8) =
                        make_uint2(vv.z, vv.w);
                }
            }
        }
    }
}

// ---------------------------------------------------------------------------
// K2: fused score+softmax+aggregate (unchanged from R8). One 32-lane
// half-wave per node; one uint4 gather per edge gives 4 e_src + 4 feat bf16
// per lane. Static softmax bound M = b2 + sum|w2|; 4-edge ILP.
// Writes neigh bf16 to abig[:, 128:].
// ---------------------------------------------------------------------------
__global__ __launch_bounds__(256) void fused_kernel(
    const ushort_t* __restrict__ e_dst, const ushort_t* __restrict__ srcpack,
    const int* __restrict__ src, const int* __restrict__ row_ptr,
    const float* __restrict__ w2, ushort_t* __restrict__ abig, int n)
{
    const int v = (int)((blockIdx.x * 256u + threadIdx.x) >> 5);
    const int fl = threadIdx.x & 31;
    const int sbase = threadIdx.x & 32;

    const float4 wv4 = ((const float4*)w2)[fl];
    const float w0 = wv4.x, w1_ = wv4.y, w2_ = wv4.z, w3_ = wv4.w;
    float sw = w0 + w1_ + w2_ + w3_;
    float aw = fabsf(w0) + fabsf(w1_) + fabsf(w2_) + fabsf(w3_);
#pragma unroll
    for (int off = 16; off; off >>= 1) {
        sw += __shfl_xor(sw, off, 64);
        aw += __shfl_xor(aw, off, 64);
    }
    const float K = sw - aw;           // score - M = K - 2*pv  (always <= 0)

    if (v >= n) return;
    const int begin = row_ptr[v], end = row_ptr[v + 1];

    const uint2 ud = *(const uint2*)(e_dst + (size_t)v * F + fl * 4);
    const float ea0 = bf_lo(ud.x), ea1 = bf_hi(ud.x);
    const float ea2 = bf_lo(ud.y), ea3 = bf_hi(ud.y);

    float s = 0.f, a0 = 0.f, a1 = 0.f, a2 = 0.f, a3 = 0.f;

    for (int cb = begin; cb < end; cb += 32) {
        const int clen = min(32, end - cb);
        const int sv = (fl < clen) ? src[cb + fl] : 0;
        int jj = 0;
        for (; jj + 4 <= clen; jj += 4) {
            uint4 u[4];
#pragma unroll
            for (int q = 0; q < 4; ++q) {
                const int sq = __shfl(sv, sbase + jj + q, 64);
                u[q] = ((const uint4*)(srcpack + (size_t)sq * 256))[fl];
            }
            float p[4];
#pragma unroll
            for (int q = 0; q < 4; ++q) {
                float r;
                r = __builtin_amdgcn_rcpf(fmaf(ea0, bf_lo(u[q].x), 1.f)); p[q] = w0 * r;
                r = __builtin_amdgcn_rcpf(fmaf(ea1, bf_hi(u[q].x), 1.f)); p[q] = fmaf(w1_, r, p[q]);
                r = __builtin_amdgcn_rcpf(fmaf(ea2, bf_lo(u[q].y), 1.f)); p[q] = fmaf(w2_, r, p[q]);
                r = __builtin_amdgcn_rcpf(fmaf(ea3, bf_hi(u[q].y), 1.f)); p[q] = fmaf(w3_, r, p[q]);
            }
#pragma unroll
            for (int off = 16; off; off >>= 1) {
#pragma unroll
                for (int q = 0; q < 4; ++q) p[q] += __shfl_xor(p[q], off, 64);
            }
            float g[4];
#pragma unroll
            for (int q = 0; q < 4; ++q) g[q] = __expf(fmaf(-2.f, p[q], K));
            s += (g[0] + g[1]) + (g[2] + g[3]);
#pragma unroll
            for (int q = 0; q < 4; ++q) {
                a0 = fmaf(g[q], bf_lo(u[q].z), a0);
                a1 = fmaf(g[q], bf_hi(u[q].z), a1);
                a2 = fmaf(g[q], bf_lo(u[q].w), a2);
                a3 = fmaf(g[q], bf_hi(u[q].w), a3);
            }
        }
        for (; jj < clen; ++jj) {
            const int s0 = __shfl(sv, sbase + jj, 64);
            const uint4 u0 = ((const uint4*)(srcpack + (size_t)s0 * 256))[fl];
            float r, p0;
            r = __builtin_amdgcn_rcpf(fmaf(ea0, bf_lo(u0.x), 1.f)); p0 = w0 * r;
            r = __builtin_amdgcn_rcpf(fmaf(ea1, bf_hi(u0.x), 1.f)); p0 = fmaf(w1_, r, p0);
            r = __builtin_amdgcn_rcpf(fmaf(ea2, bf_lo(u0.y), 1.f)); p0 = fmaf(w2_, r, p0);
            r = __builtin_amdgcn_rcpf(fmaf(ea3, bf_hi(u0.y), 1.f)); p0 = fmaf(w3_, r, p0);
#pragma unroll
            for (int off = 16; off; off >>= 1) p0 += __shfl_xor(p0, off, 64);
            const float g0 = __expf(fmaf(-2.f, p0, K));
            s += g0;
            a0 = fmaf(g0, bf_lo(u0.z), a0);
            a1 = fmaf(g0, bf_hi(u0.z), a1);
            a2 = fmaf(g0, bf_lo(u0.w), a2);
            a3 = fmaf(g0, bf_hi(u0.w), a3);
        }
    }

    const float inv = (end > begin) ? 1.f / s : 0.f;
    ushort4 o = make_ushort4(f2bf(a0 * inv), f2bf(a1 * inv),
                             f2bf(a2 * inv), f2bf(a3 * inv));
    *(ushort4*)(abig + (size_t)v * 256 + 128 + fl * 4) = o;
}

// ---------------------------------------------------------------------------
// G2 (out): out[n x 128] = abig(bf16, K=256) @ btf + bf.
// Block = 64 rows x 128 cols, 4 waves (wave w: cols 32w..32w+31).
// B-fragments hoisted; fp32 output stores are naturally coalesced.
// ---------------------------------------------------------------------------
#define OST 280
__global__ __launch_bounds__(256) void out_gemm_kernel(
    const ushort_t* __restrict__ abig, const ushort_t* __restrict__ btf,
    const float* __restrict__ bfv, float* __restrict__ out, int n)
{
    __shared__ ushort_t As[64 * OST];        // 35840 B
    const int t = threadIdx.x;
    const int wv = t >> 6, lane = t & 63;
    const int lm = lane & 15, quad = lane >> 4;
    const int row0 = blockIdx.x * 64, col0 = wv * 32;

#pragma unroll
    for (int k = 0; k < 8; ++k) {            // 64 rows x 32 uint4, coalesced
        int l = k * 256 + t;
        int r = l >> 5, ch = l & 31;
        uint4 d = make_uint4(0, 0, 0, 0);
        if (row0 + r < n) d = *(const uint4*)(abig + (size_t)(row0 + r) * 256 + ch * 8);
        *(uint4*)(As + r * OST + ch * 8) = d;
    }
    __syncthreads();

    bfrag bfr[8][2];
#pragma unroll
    for (int ks = 0; ks < 8; ++ks)
#pragma unroll
        for (int ni = 0; ni < 2; ++ni)
            bfr[ks][ni] = *(const bfrag*)(btf + (size_t)(col0 + ni * 16 + lm) * 256
                                          + ks * 32 + quad * 8);

    ffrag acc[4][2];
#pragma unroll
    for (int mi = 0; mi < 4; ++mi)
#pragma unroll
        for (int ni = 0; ni < 2; ++ni) acc[mi][ni] = (ffrag){0.f, 0.f, 0.f, 0.f};

#pragma unroll
    for (int ks = 0; ks < 8; ++ks)
#pragma unroll
        for (int mi = 0; mi < 4; ++mi) {
            bfrag af = *(const bfrag*)(As + (mi * 16 + lm) * OST + ks * 32 + quad * 8);
#pragma unroll
            for (int ni = 0; ni < 2; ++ni)
                acc[mi][ni] = __builtin_amdgcn_mfma_f32_16x16x32_bf16(
                    af, bfr[ks][ni], acc[mi][ni], 0, 0, 0);
        }

#pragma unroll
    for (int ni = 0; ni < 2; ++ni) {
        const int j = col0 + ni * 16 + lm;
        const float bb = bfv[j];
#pragma unroll
        for (int mi = 0; mi < 4; ++mi)
#pragma unroll
            for (int r = 0; r < 4; ++r) {
                int grow = row0 + mi * 16 + quad * 4 + r;
                if (grow < n) out[(size_t)grow * OUT + j] = acc[mi][ni][r] + bb;
            }
    }
}

// ---------------------------------------------------------------------------
extern "C" void kernel_launch(void* const* d_in, const int* in_sizes, int n_in,
                              void* d_out, int out_size, void* d_ws, size_t ws_size,
                              hipStream_t stream)
{
    const float* feat = (const float*)d_in[0];
    const int*   src  = (const int*)d_in[1];
    const int*   dst  = (const int*)d_in[2];
    const float* w1   = (const float*)d_in[3];
    const float* b1   = (const float*)d_in[4];
    const float* w2   = (const float*)d_in[5];
    const float* b2   = (const float*)d_in[6];  (void)b2; // cancels in softmax
    const float* wf   = (const float*)d_in[7];
    const float* bfv  = (const float*)d_in[8];
    float* out = (float*)d_out;

    const int n = in_sizes[0] / F;   // 40000
    const int e = in_sizes[1];       // 640000

    ushort_t* abig    = (ushort_t*)d_ws;                   // n*256 bf16 [feat|neigh]
    ushort_t* e_dst   = abig + (size_t)n * 256;            // n*128 bf16
    ushort_t* srcpack = e_dst + (size_t)n * 128;           // n*256 bf16 interleaved
    ushort_t* btp     = srcpack + (size_t)n * 256;         // 256*128 bf16 col-major
    ushort_t* btf     = btp + 32768;                       // 128*256 bf16 col-major
    int* row_ptr      = (int*)(btf + 32768);               // n+1

    const int nb0 = (n * 16 + 255) / 256;   // 2500
    const int nb1 = 128, nb2 = 128;
    const int nb3 = (e + 255) / 256;        // 2500

    prep_kernel<<<nb0 + nb1 + nb2 + nb3, 256, 0, stream>>>(
        feat, w1, wf, dst, abig, srcpack, btp, btf, row_ptr, n, e, nb0, nb1, nb2);
    proj_gemm_kernel<<<(n + 63) / 64, 256, 0, stream>>>(
        abig, btp, b1, e_dst, srcpack, n);
    fused_kernel<<<(n + 7) / 8, 256, 0, stream>>>(
        e_dst, srcpack, src, row_ptr, w2, abig, n);
    out_gemm_kernel<<<(n + 63) / 64, 256, 0, stream>>>(abig, btf, bfv, out, n);
}